// Round 1
// baseline (496.828 us; speedup 1.0000x reference)
//
#include <hip/hip_runtime.h>

#define HID 96

// ---------------- CSR build ----------------
__global__ void hist_kernel(const int* __restrict__ dst, int* __restrict__ cnt, int E) {
    int e = blockIdx.x * blockDim.x + threadIdx.x;
    if (e < E) atomicAdd(&cnt[dst[e]], 1);
}

__global__ __launch_bounds__(1024) void scan_kernel(const int* __restrict__ cnt,
        int* __restrict__ row_start, int* __restrict__ cursor, int n) {
    __shared__ int sums[1024];
    int t = threadIdx.x;
    const int C = (n + 1023) >> 10;
    int base = t * C;
    int local = 0;
    for (int j = 0; j < C; ++j) {
        int idx = base + j;
        if (idx < n) local += cnt[idx];
    }
    sums[t] = local;
    __syncthreads();
    // Hillis-Steele inclusive scan over 1024 chunk sums
    for (int off = 1; off < 1024; off <<= 1) {
        int v = (t >= off) ? sums[t - off] : 0;
        __syncthreads();
        sums[t] += v;
        __syncthreads();
    }
    int run = (t == 0) ? 0 : sums[t - 1];
    for (int j = 0; j < C; ++j) {
        int idx = base + j;
        if (idx < n) {
            row_start[idx] = run;
            cursor[idx] = run;
            run += cnt[idx];
        }
    }
    if (t == 1023) row_start[n] = run;  // == E
}

__global__ void scatter_kernel(const int* __restrict__ src, const int* __restrict__ dst,
        int* __restrict__ cursor, int* __restrict__ csr_src, int E) {
    int e = blockIdx.x * blockDim.x + threadIdx.x;
    if (e < E) {
        int d = dst[e];
        int slot = atomicAdd(&cursor[d], 1);
        csr_src[slot] = src[e];
    }
}

__global__ void dinv_kernel(const int* __restrict__ cnt, float* __restrict__ dinv, int n) {
    int i = blockIdx.x * blockDim.x + threadIdx.x;
    if (i < n) dinv[i] = 1.0f / sqrtf((float)(cnt[i] + 1));  // +1 self-loop
}

// ---------------- dense GEMM: hs[i,:] = dinv[i] * (in[i,:] @ W) ----------------
// block = 256 threads, 64 rows/block, micro-tile 4 rows x 6 cols per thread.
__global__ __launch_bounds__(256) void gemm_scale(const float* __restrict__ in,
        const float* __restrict__ W, const float* __restrict__ dinv,
        float* __restrict__ out, int n) {
    __shared__ float Ws[96][96];   // 36864 B
    __shared__ float Xs[64][98];   // padded stride 98 -> banks {0,8,16,24}, conflict-free
    int t = threadIdx.x;
    for (int idx = t; idx < 96 * 96; idx += 256) Ws[idx / 96][idx % 96] = W[idx];
    int row0 = blockIdx.x * 64;
    for (int idx = t; idx < 64 * 96; idx += 256) {
        int r = idx / 96, c = idx % 96;
        int gr = row0 + r;
        Xs[r][c] = (gr < n) ? in[gr * 96 + c] : 0.f;
    }
    __syncthreads();
    int ty = t >> 4, tx = t & 15;   // 16x16 threads
    float acc[4][6];
#pragma unroll
    for (int i = 0; i < 4; ++i)
#pragma unroll
        for (int j = 0; j < 6; ++j) acc[i][j] = 0.f;
#pragma unroll 4
    for (int k = 0; k < 96; ++k) {
        float xv[4], wv[6];
#pragma unroll
        for (int i = 0; i < 4; ++i) xv[i] = Xs[ty * 4 + i][k];
#pragma unroll
        for (int j = 0; j < 6; ++j) wv[j] = Ws[k][tx * 6 + j];
#pragma unroll
        for (int i = 0; i < 4; ++i)
#pragma unroll
            for (int j = 0; j < 6; ++j) acc[i][j] = fmaf(xv[i], wv[j], acc[i][j]);
    }
#pragma unroll
    for (int i = 0; i < 4; ++i) {
        int gr = row0 + ty * 4 + i;
        if (gr < n) {
            float dv = dinv[gr];
#pragma unroll
            for (int j = 0; j < 6; ++j) out[gr * 96 + tx * 6 + j] = dv * acc[i][j];
        }
    }
}

// ---------------- gather aggregation + scale + bias + relu ----------------
// out[i,:] = relu(dinv[i] * (hs[i,:] + sum_{e in(i)} hs[csr_src[e],:]) + b)
// one thread per (node, float4-chunk): 24 chunks/row
__global__ void gather_kernel(const float4* __restrict__ hs, const int* __restrict__ row_start,
        const int* __restrict__ csr_src, const float* __restrict__ dinv,
        const float* __restrict__ bias, float4* __restrict__ out, int n) {
    int gid = blockIdx.x * blockDim.x + threadIdx.x;
    if (gid >= n * 24) return;
    int i = gid / 24, q = gid - i * 24;
    float4 acc = hs[i * 24 + q];                 // self-loop term
    int e1 = row_start[i + 1];
    for (int e = row_start[i]; e < e1; ++e) {
        int s = csr_src[e];
        float4 v = hs[s * 24 + q];
        acc.x += v.x; acc.y += v.y; acc.z += v.z; acc.w += v.w;
    }
    float dv = dinv[i];
    const float4 bb = reinterpret_cast<const float4*>(bias)[q];
    float4 r;
    r.x = fmaxf(fmaf(acc.x, dv, bb.x), 0.f);
    r.y = fmaxf(fmaf(acc.y, dv, bb.y), 0.f);
    r.z = fmaxf(fmaf(acc.z, dv, bb.z), 0.f);
    r.w = fmaxf(fmaf(acc.w, dv, bb.w), 0.f);
    out[i * 24 + q] = r;
}

// ---------------- column-sum of h2 [n x 96] into per-block partials ----------------
__global__ __launch_bounds__(192) void colsum_kernel(const float* __restrict__ h2,
        float* __restrict__ partials, int n) {
    int c = threadIdx.x % 96;
    int rs = threadIdx.x / 96;  // 0 or 1
    float acc = 0.f;
    for (int r = blockIdx.x * 2 + rs; r < n; r += gridDim.x * 2)
        acc += h2[r * 96 + c];
    __shared__ float red[96];
    if (rs == 1) red[c] = acc;
    __syncthreads();
    if (rs == 0) partials[blockIdx.x * 96 + c] = acc + red[c];
}

// ---------------- final MLP heads (single block) ----------------
__global__ __launch_bounds__(128) void head_kernel(const float* __restrict__ partials,
        int nparts, int n,
        const float* __restrict__ lin_w, const float* __restrict__ lin_b,
        const float* __restrict__ q_w, const float* __restrict__ q_b,
        const float* __restrict__ g_w, const float* __restrict__ g_b,
        const float* __restrict__ p_w, const float* __restrict__ p_b,
        const float* __restrict__ t_w, const float* __restrict__ t_b,
        float* __restrict__ out) {
    __shared__ float hm[96];
    __shared__ float h[96];
    int t = threadIdx.x;
    if (t < 96) {
        float s = 0.f;
        for (int b = 0; b < nparts; ++b) s += partials[b * 96 + t];
        hm[t] = s / (float)n;
    }
    __syncthreads();
    if (t < 96) {
        float s = lin_b[t];
        for (int k = 0; k < 96; ++k) s = fmaf(hm[k], lin_w[k * 96 + t], s);
        h[t] = fmaxf(s, 0.f);
    }
    __syncthreads();
    if (t < 43) {
        float s;
        if (t < 16) {
            s = q_b[t];
            for (int k = 0; k < 96; ++k) s = fmaf(h[k], q_w[k * 16 + t], s);
        } else if (t < 24) {
            int j = t - 16;
            s = g_b[j];
            for (int k = 0; k < 96; ++k) s = fmaf(h[k], g_w[k * 8 + j], s);
        } else if (t < 28) {
            int j = t - 24;
            s = p_b[j];
            for (int k = 0; k < 96; ++k) s = fmaf(h[k], p_w[k * 4 + j], s);
        } else {
            int j = t - 28;
            s = t_b[j];
            for (int k = 0; k < 96; ++k) s = fmaf(h[k], t_w[k * 15 + j], s);
        }
        out[t] = s;
    }
}

extern "C" void kernel_launch(void* const* d_in, const int* in_sizes, int n_in,
                              void* d_out, int out_size, void* d_ws, size_t ws_size,
                              hipStream_t stream) {
    const float* x     = (const float*)d_in[0];
    const int*   edges = (const int*)d_in[1];
    const float* W1    = (const float*)d_in[2];
    const float* b1    = (const float*)d_in[3];
    const float* W2    = (const float*)d_in[4];
    const float* b2    = (const float*)d_in[5];
    const float* lin_w = (const float*)d_in[6];
    const float* lin_b = (const float*)d_in[7];
    const float* q_w   = (const float*)d_in[8];
    const float* q_b   = (const float*)d_in[9];
    const float* g_w   = (const float*)d_in[10];
    const float* g_b   = (const float*)d_in[11];
    const float* p_w   = (const float*)d_in[12];
    const float* p_b   = (const float*)d_in[13];
    const float* t_w   = (const float*)d_in[14];
    const float* t_b   = (const float*)d_in[15];

    const int N = in_sizes[0] / HID;   // 50000
    const int E = in_sizes[1] / 2;     // 800000
    const int* src = edges;
    const int* dst = edges + E;

    char* w = (char*)d_ws;
    auto carve = [&](size_t bytes) {
        char* p = w;
        w += (bytes + 255) & ~size_t(255);
        return (void*)p;
    };
    float* hs        = (float*)carve((size_t)N * HID * 4);
    float* hbuf      = (float*)carve((size_t)N * HID * 4);
    float* dinv      = (float*)carve((size_t)N * 4);
    int*   cnt       = (int*)  carve((size_t)N * 4);
    int*   row_start = (int*)  carve((size_t)(N + 1) * 4);
    int*   cursor    = (int*)  carve((size_t)N * 4);
    int*   csr_src   = (int*)  carve((size_t)E * 4);
    float* partials  = (float*)carve((size_t)128 * HID * 4);

    // CSR build + dinv
    hipMemsetAsync(cnt, 0, (size_t)N * 4, stream);
    hist_kernel<<<(E + 255) / 256, 256, 0, stream>>>(dst, cnt, E);
    scan_kernel<<<1, 1024, 0, stream>>>(cnt, row_start, cursor, N);
    dinv_kernel<<<(N + 255) / 256, 256, 0, stream>>>(cnt, dinv, N);
    scatter_kernel<<<(E + 255) / 256, 256, 0, stream>>>(src, dst, cursor, csr_src, E);

    int gemm_blocks = (N + 63) / 64;
    int gthreads = N * 24;

    // layer 1
    gemm_scale<<<gemm_blocks, 256, 0, stream>>>(x, W1, dinv, hs, N);
    gather_kernel<<<(gthreads + 255) / 256, 256, 0, stream>>>(
        (const float4*)hs, row_start, csr_src, dinv, b1, (float4*)hbuf, N);
    // layer 2
    gemm_scale<<<gemm_blocks, 256, 0, stream>>>(hbuf, W2, dinv, hs, N);
    gather_kernel<<<(gthreads + 255) / 256, 256, 0, stream>>>(
        (const float4*)hs, row_start, csr_src, dinv, b2, (float4*)hbuf, N);

    // pool + heads
    colsum_kernel<<<128, 192, 0, stream>>>(hbuf, partials, N);
    head_kernel<<<1, 128, 0, stream>>>(partials, 128, N, lin_w, lin_b,
        q_w, q_b, g_w, g_b, p_w, p_b, t_w, t_b, (float*)d_out);
}

// Round 2
// 383.998 us; speedup vs baseline: 1.2938x; 1.2938x over previous
//
#include <hip/hip_runtime.h>

#define HID 96
#define SCAN_BLOCK 256
#define SCAN_CHUNK 8   // elements per thread; 2048 per block

// ---------------- CSR build ----------------
__global__ void hist_kernel(const int* __restrict__ dst, int* __restrict__ cnt, int E) {
    int e = blockIdx.x * blockDim.x + threadIdx.x;
    if (e < E) atomicAdd(&cnt[dst[e]], 1);
}

// phase 1: per-block sums of cnt
__global__ __launch_bounds__(SCAN_BLOCK) void scan_partial(const int* __restrict__ cnt,
        int* __restrict__ blocksums, int n) {
    int base = (blockIdx.x * SCAN_BLOCK + threadIdx.x) * SCAN_CHUNK;
    int s = 0;
#pragma unroll
    for (int j = 0; j < SCAN_CHUNK; ++j) {
        int idx = base + j;
        if (idx < n) s += cnt[idx];
    }
    __shared__ int red[SCAN_BLOCK];
    red[threadIdx.x] = s;
    __syncthreads();
    for (int off = SCAN_BLOCK / 2; off > 0; off >>= 1) {
        if (threadIdx.x < off) red[threadIdx.x] += red[threadIdx.x + off];
        __syncthreads();
    }
    if (threadIdx.x == 0) blocksums[blockIdx.x] = red[0];
}

// phase 2: exclusive scan of block sums (single small block; nb <= 1024)
__global__ __launch_bounds__(1024) void scan_sums(int* __restrict__ blocksums, int nb) {
    __shared__ int sh[1024];
    int t = threadIdx.x;
    sh[t] = (t < nb) ? blocksums[t] : 0;
    __syncthreads();
    for (int off = 1; off < 1024; off <<= 1) {
        int v = (t >= off) ? sh[t - off] : 0;
        __syncthreads();
        sh[t] += v;
        __syncthreads();
    }
    if (t < nb) blocksums[t] = (t == 0) ? 0 : sh[t - 1];
}

// phase 3: expand — write row_start/cursor, plus dinv (reads cnt anyway)
__global__ __launch_bounds__(SCAN_BLOCK) void scan_expand(const int* __restrict__ cnt,
        const int* __restrict__ blocksums, int* __restrict__ row_start,
        int* __restrict__ cursor, float* __restrict__ dinv, int n, int E) {
    int t = threadIdx.x;
    int tbase = (blockIdx.x * SCAN_BLOCK + t) * SCAN_CHUNK;
    int local[SCAN_CHUNK];
    int s = 0;
#pragma unroll
    for (int j = 0; j < SCAN_CHUNK; ++j) {
        int idx = tbase + j;
        int c = (idx < n) ? cnt[idx] : 0;
        local[j] = c;
        s += c;
    }
    __shared__ int sh[SCAN_BLOCK];
    sh[t] = s;
    __syncthreads();
    for (int off = 1; off < SCAN_BLOCK; off <<= 1) {
        int v = (t >= off) ? sh[t - off] : 0;
        __syncthreads();
        sh[t] += v;
        __syncthreads();
    }
    int run = blocksums[blockIdx.x] + ((t == 0) ? 0 : sh[t - 1]);
#pragma unroll
    for (int j = 0; j < SCAN_CHUNK; ++j) {
        int idx = tbase + j;
        if (idx < n) {
            row_start[idx] = run;
            cursor[idx] = run;
            dinv[idx] = 1.0f / sqrtf((float)(local[j] + 1));  // +1 self-loop
            run += local[j];
        }
    }
    if (blockIdx.x == 0 && t == 0) row_start[n] = E;
}

__global__ void scatter_kernel(const int* __restrict__ src, const int* __restrict__ dst,
        int* __restrict__ cursor, int* __restrict__ csr_src, int E) {
    int e = blockIdx.x * blockDim.x + threadIdx.x;
    if (e < E) {
        int d = dst[e];
        int slot = atomicAdd(&cursor[d], 1);
        csr_src[slot] = src[e];
    }
}

// ---------------- dense GEMM: hs[i,:] = dinv[i] * (in[i,:] @ W) ----------------
__global__ __launch_bounds__(256) void gemm_scale(const float* __restrict__ in,
        const float* __restrict__ W, const float* __restrict__ dinv,
        float* __restrict__ out, int n) {
    __shared__ float Ws[96][96];
    __shared__ float Xs[64][98];
    int t = threadIdx.x;
    for (int idx = t; idx < 96 * 96; idx += 256) Ws[idx / 96][idx % 96] = W[idx];
    int row0 = blockIdx.x * 64;
    for (int idx = t; idx < 64 * 96; idx += 256) {
        int r = idx / 96, c = idx % 96;
        int gr = row0 + r;
        Xs[r][c] = (gr < n) ? in[gr * 96 + c] : 0.f;
    }
    __syncthreads();
    int ty = t >> 4, tx = t & 15;
    float acc[4][6];
#pragma unroll
    for (int i = 0; i < 4; ++i)
#pragma unroll
        for (int j = 0; j < 6; ++j) acc[i][j] = 0.f;
#pragma unroll 4
    for (int k = 0; k < 96; ++k) {
        float xv[4], wv[6];
#pragma unroll
        for (int i = 0; i < 4; ++i) xv[i] = Xs[ty * 4 + i][k];
#pragma unroll
        for (int j = 0; j < 6; ++j) wv[j] = Ws[k][tx * 6 + j];
#pragma unroll
        for (int i = 0; i < 4; ++i)
#pragma unroll
            for (int j = 0; j < 6; ++j) acc[i][j] = fmaf(xv[i], wv[j], acc[i][j]);
    }
#pragma unroll
    for (int i = 0; i < 4; ++i) {
        int gr = row0 + ty * 4 + i;
        if (gr < n) {
            float dv = dinv[gr];
#pragma unroll
            for (int j = 0; j < 6; ++j) out[gr * 96 + tx * 6 + j] = dv * acc[i][j];
        }
    }
}

// ---------------- gather aggregation + scale + bias + relu ----------------
__global__ void gather_kernel(const float4* __restrict__ hs, const int* __restrict__ row_start,
        const int* __restrict__ csr_src, const float* __restrict__ dinv,
        const float* __restrict__ bias, float4* __restrict__ out, int n) {
    int gid = blockIdx.x * blockDim.x + threadIdx.x;
    if (gid >= n * 24) return;
    int i = gid / 24, q = gid - i * 24;
    float4 acc = hs[i * 24 + q];                 // self-loop term
    int e1 = row_start[i + 1];
    for (int e = row_start[i]; e < e1; ++e) {
        int s = csr_src[e];
        float4 v = hs[s * 24 + q];
        acc.x += v.x; acc.y += v.y; acc.z += v.z; acc.w += v.w;
    }
    float dv = dinv[i];
    const float4 bb = reinterpret_cast<const float4*>(bias)[q];
    float4 r;
    r.x = fmaxf(fmaf(acc.x, dv, bb.x), 0.f);
    r.y = fmaxf(fmaf(acc.y, dv, bb.y), 0.f);
    r.z = fmaxf(fmaf(acc.z, dv, bb.z), 0.f);
    r.w = fmaxf(fmaf(acc.w, dv, bb.w), 0.f);
    out[i * 24 + q] = r;
}

// ---------------- column-sum of h2 [n x 96] into per-block partials ----------------
__global__ __launch_bounds__(192) void colsum_kernel(const float* __restrict__ h2,
        float* __restrict__ partials, int n) {
    int c = threadIdx.x % 96;
    int rs = threadIdx.x / 96;
    float acc = 0.f;
    for (int r = blockIdx.x * 2 + rs; r < n; r += gridDim.x * 2)
        acc += h2[r * 96 + c];
    __shared__ float red[96];
    if (rs == 1) red[c] = acc;
    __syncthreads();
    if (rs == 0) partials[blockIdx.x * 96 + c] = acc + red[c];
}

// ---------------- final MLP heads (single block) ----------------
__global__ __launch_bounds__(128) void head_kernel(const float* __restrict__ partials,
        int nparts, int n,
        const float* __restrict__ lin_w, const float* __restrict__ lin_b,
        const float* __restrict__ q_w, const float* __restrict__ q_b,
        const float* __restrict__ g_w, const float* __restrict__ g_b,
        const float* __restrict__ p_w, const float* __restrict__ p_b,
        const float* __restrict__ t_w, const float* __restrict__ t_b,
        float* __restrict__ out) {
    __shared__ float hm[96];
    __shared__ float h[96];
    int t = threadIdx.x;
    if (t < 96) {
        float s = 0.f;
        for (int b = 0; b < nparts; ++b) s += partials[b * 96 + t];
        hm[t] = s / (float)n;
    }
    __syncthreads();
    if (t < 96) {
        float s = lin_b[t];
        for (int k = 0; k < 96; ++k) s = fmaf(hm[k], lin_w[k * 96 + t], s);
        h[t] = fmaxf(s, 0.f);
    }
    __syncthreads();
    if (t < 43) {
        float s;
        if (t < 16) {
            s = q_b[t];
            for (int k = 0; k < 96; ++k) s = fmaf(h[k], q_w[k * 16 + t], s);
        } else if (t < 24) {
            int j = t - 16;
            s = g_b[j];
            for (int k = 0; k < 96; ++k) s = fmaf(h[k], g_w[k * 8 + j], s);
        } else if (t < 28) {
            int j = t - 24;
            s = p_b[j];
            for (int k = 0; k < 96; ++k) s = fmaf(h[k], p_w[k * 4 + j], s);
        } else {
            int j = t - 28;
            s = t_b[j];
            for (int k = 0; k < 96; ++k) s = fmaf(h[k], t_w[k * 15 + j], s);
        }
        out[t] = s;
    }
}

extern "C" void kernel_launch(void* const* d_in, const int* in_sizes, int n_in,
                              void* d_out, int out_size, void* d_ws, size_t ws_size,
                              hipStream_t stream) {
    const float* x     = (const float*)d_in[0];
    const int*   edges = (const int*)d_in[1];
    const float* W1    = (const float*)d_in[2];
    const float* b1    = (const float*)d_in[3];
    const float* W2    = (const float*)d_in[4];
    const float* b2    = (const float*)d_in[5];
    const float* lin_w = (const float*)d_in[6];
    const float* lin_b = (const float*)d_in[7];
    const float* q_w   = (const float*)d_in[8];
    const float* q_b   = (const float*)d_in[9];
    const float* g_w   = (const float*)d_in[10];
    const float* g_b   = (const float*)d_in[11];
    const float* p_w   = (const float*)d_in[12];
    const float* p_b   = (const float*)d_in[13];
    const float* t_w   = (const float*)d_in[14];
    const float* t_b   = (const float*)d_in[15];

    const int N = in_sizes[0] / HID;   // 50000
    const int E = in_sizes[1] / 2;     // 800000
    const int* src = edges;
    const int* dst = edges + E;

    char* w = (char*)d_ws;
    auto carve = [&](size_t bytes) {
        char* p = w;
        w += (bytes + 255) & ~size_t(255);
        return (void*)p;
    };
    float* hs        = (float*)carve((size_t)N * HID * 4);
    float* hbuf      = (float*)carve((size_t)N * HID * 4);
    float* dinv      = (float*)carve((size_t)N * 4);
    int*   cnt       = (int*)  carve((size_t)N * 4);
    int*   row_start = (int*)  carve((size_t)(N + 1) * 4);
    int*   cursor    = (int*)  carve((size_t)N * 4);
    int*   csr_src   = (int*)  carve((size_t)E * 4);
    float* partials  = (float*)carve((size_t)128 * HID * 4);
    int*   blocksums = (int*)  carve((size_t)1024 * 4);

    const int elems_per_blk = SCAN_BLOCK * SCAN_CHUNK;          // 2048
    const int scan_blocks = (N + elems_per_blk - 1) / elems_per_blk;  // 25

    // CSR build + dinv
    hipMemsetAsync(cnt, 0, (size_t)N * 4, stream);
    hist_kernel<<<(E + 255) / 256, 256, 0, stream>>>(dst, cnt, E);
    scan_partial<<<scan_blocks, SCAN_BLOCK, 0, stream>>>(cnt, blocksums, N);
    scan_sums<<<1, 1024, 0, stream>>>(blocksums, scan_blocks);
    scan_expand<<<scan_blocks, SCAN_BLOCK, 0, stream>>>(cnt, blocksums, row_start,
                                                        cursor, dinv, N, E);
    scatter_kernel<<<(E + 255) / 256, 256, 0, stream>>>(src, dst, cursor, csr_src, E);

    int gemm_blocks = (N + 63) / 64;
    int gthreads = N * 24;

    // layer 1
    gemm_scale<<<gemm_blocks, 256, 0, stream>>>(x, W1, dinv, hs, N);
    gather_kernel<<<(gthreads + 255) / 256, 256, 0, stream>>>(
        (const float4*)hs, row_start, csr_src, dinv, b1, (float4*)hbuf, N);
    // layer 2
    gemm_scale<<<gemm_blocks, 256, 0, stream>>>(hbuf, W2, dinv, hs, N);
    gather_kernel<<<(gthreads + 255) / 256, 256, 0, stream>>>(
        (const float4*)hs, row_start, csr_src, dinv, b2, (float4*)hbuf, N);

    // pool + heads
    colsum_kernel<<<128, 192, 0, stream>>>(hbuf, partials, N);
    head_kernel<<<1, 128, 0, stream>>>(partials, 128, N, lin_w, lin_b,
        q_w, q_b, g_w, g_b, p_w, p_b, t_w, t_b, (float*)d_out);
}

// Round 3
// 303.313 us; speedup vs baseline: 1.6380x; 1.2660x over previous
//
#include <hip/hip_runtime.h>

#define HID 96
#define SCAN_BLOCK 256
#define SCAN_CHUNK 8   // elements per thread; 2048 per block
#define CS_BLOCKS 768  // colsum grid (3 per CU)

// ---------------- CSR build ----------------
__global__ void hist_kernel(const int* __restrict__ dst, int* __restrict__ cnt, int E) {
    int e = blockIdx.x * blockDim.x + threadIdx.x;
    if (e < E) atomicAdd(&cnt[dst[e]], 1);
}

// phase 1: per-block sums of cnt
__global__ __launch_bounds__(SCAN_BLOCK) void scan_partial(const int* __restrict__ cnt,
        int* __restrict__ blocksums, int n) {
    int base = (blockIdx.x * SCAN_BLOCK + threadIdx.x) * SCAN_CHUNK;
    int s = 0;
#pragma unroll
    for (int j = 0; j < SCAN_CHUNK; ++j) {
        int idx = base + j;
        if (idx < n) s += cnt[idx];
    }
    __shared__ int red[SCAN_BLOCK];
    red[threadIdx.x] = s;
    __syncthreads();
    for (int off = SCAN_BLOCK / 2; off > 0; off >>= 1) {
        if (threadIdx.x < off) red[threadIdx.x] += red[threadIdx.x + off];
        __syncthreads();
    }
    if (threadIdx.x == 0) blocksums[blockIdx.x] = red[0];
}

// phase 2: exclusive scan of block sums (single small block; nb <= 1024)
__global__ __launch_bounds__(1024) void scan_sums(int* __restrict__ blocksums, int nb) {
    __shared__ int sh[1024];
    int t = threadIdx.x;
    sh[t] = (t < nb) ? blocksums[t] : 0;
    __syncthreads();
    for (int off = 1; off < 1024; off <<= 1) {
        int v = (t >= off) ? sh[t - off] : 0;
        __syncthreads();
        sh[t] += v;
        __syncthreads();
    }
    if (t < nb) blocksums[t] = (t == 0) ? 0 : sh[t - 1];
}

// phase 3: expand — write row_start/cursor, plus dinv (reads cnt anyway)
__global__ __launch_bounds__(SCAN_BLOCK) void scan_expand(const int* __restrict__ cnt,
        const int* __restrict__ blocksums, int* __restrict__ row_start,
        int* __restrict__ cursor, float* __restrict__ dinv, int n, int E) {
    int t = threadIdx.x;
    int tbase = (blockIdx.x * SCAN_BLOCK + t) * SCAN_CHUNK;
    int local[SCAN_CHUNK];
    int s = 0;
#pragma unroll
    for (int j = 0; j < SCAN_CHUNK; ++j) {
        int idx = tbase + j;
        int c = (idx < n) ? cnt[idx] : 0;
        local[j] = c;
        s += c;
    }
    __shared__ int sh[SCAN_BLOCK];
    sh[t] = s;
    __syncthreads();
    for (int off = 1; off < SCAN_BLOCK; off <<= 1) {
        int v = (t >= off) ? sh[t - off] : 0;
        __syncthreads();
        sh[t] += v;
        __syncthreads();
    }
    int run = blocksums[blockIdx.x] + ((t == 0) ? 0 : sh[t - 1]);
#pragma unroll
    for (int j = 0; j < SCAN_CHUNK; ++j) {
        int idx = tbase + j;
        if (idx < n) {
            row_start[idx] = run;
            cursor[idx] = run;
            dinv[idx] = 1.0f / sqrtf((float)(local[j] + 1));  // +1 self-loop
            run += local[j];
        }
    }
    if (blockIdx.x == 0 && t == 0) row_start[n] = E;
}

__global__ void scatter_kernel(const int* __restrict__ src, const int* __restrict__ dst,
        int* __restrict__ cursor, int* __restrict__ csr_src, int E) {
    int e = blockIdx.x * blockDim.x + threadIdx.x;
    if (e < E) {
        int d = dst[e];
        int slot = atomicAdd(&cursor[d], 1);
        csr_src[slot] = src[e];
    }
}

// ---------------- dense GEMM: hs[i,:] = dinv[i] * (in[i,:] @ W) ----------------
__global__ __launch_bounds__(256) void gemm_scale(const float* __restrict__ in,
        const float* __restrict__ W, const float* __restrict__ dinv,
        float* __restrict__ out, int n) {
    __shared__ float Ws[96][96];
    __shared__ float Xs[64][98];
    int t = threadIdx.x;
    for (int idx = t; idx < 96 * 96; idx += 256) Ws[idx / 96][idx % 96] = W[idx];
    int row0 = blockIdx.x * 64;
    for (int idx = t; idx < 64 * 96; idx += 256) {
        int r = idx / 96, c = idx % 96;
        int gr = row0 + r;
        Xs[r][c] = (gr < n) ? in[gr * 96 + c] : 0.f;
    }
    __syncthreads();
    int ty = t >> 4, tx = t & 15;
    float acc[4][6];
#pragma unroll
    for (int i = 0; i < 4; ++i)
#pragma unroll
        for (int j = 0; j < 6; ++j) acc[i][j] = 0.f;
#pragma unroll 4
    for (int k = 0; k < 96; ++k) {
        float xv[4], wv[6];
#pragma unroll
        for (int i = 0; i < 4; ++i) xv[i] = Xs[ty * 4 + i][k];
#pragma unroll
        for (int j = 0; j < 6; ++j) wv[j] = Ws[k][tx * 6 + j];
#pragma unroll
        for (int i = 0; i < 4; ++i)
#pragma unroll
            for (int j = 0; j < 6; ++j) acc[i][j] = fmaf(xv[i], wv[j], acc[i][j]);
    }
#pragma unroll
    for (int i = 0; i < 4; ++i) {
        int gr = row0 + ty * 4 + i;
        if (gr < n) {
            float dv = dinv[gr];
#pragma unroll
            for (int j = 0; j < 6; ++j) out[gr * 96 + tx * 6 + j] = dv * acc[i][j];
        }
    }
}

// ---------------- gather aggregation + scale + bias + relu ----------------
__global__ void gather_kernel(const float4* __restrict__ hs, const int* __restrict__ row_start,
        const int* __restrict__ csr_src, const float* __restrict__ dinv,
        const float* __restrict__ bias, float4* __restrict__ out, int n) {
    int gid = blockIdx.x * blockDim.x + threadIdx.x;
    if (gid >= n * 24) return;
    int i = gid / 24, q = gid - i * 24;
    float4 acc = hs[i * 24 + q];                 // self-loop term
    int e1 = row_start[i + 1];
    for (int e = row_start[i]; e < e1; ++e) {
        int s = csr_src[e];
        float4 v = hs[s * 24 + q];
        acc.x += v.x; acc.y += v.y; acc.z += v.z; acc.w += v.w;
    }
    float dv = dinv[i];
    const float4 bb = reinterpret_cast<const float4*>(bias)[q];
    float4 r;
    r.x = fmaxf(fmaf(acc.x, dv, bb.x), 0.f);
    r.y = fmaxf(fmaf(acc.y, dv, bb.y), 0.f);
    r.z = fmaxf(fmaf(acc.z, dv, bb.z), 0.f);
    r.w = fmaxf(fmaf(acc.w, dv, bb.w), 0.f);
    out[i * 24 + q] = r;
}

// ---------------- column-sum of h2 [n x 96]: stage 1, 768 blocks ----------------
__global__ __launch_bounds__(256) void colsum_kernel(const float4* __restrict__ h2,
        float4* __restrict__ partials, int n) {
    int q = threadIdx.x % 24;   // float4 chunk within row
    int g = threadIdx.x / 24;   // row group 0..10 (g==10: 16 idle threads)
    float4 acc = {0.f, 0.f, 0.f, 0.f};
    if (g < 10) {
        for (int r = blockIdx.x * 10 + g; r < n; r += CS_BLOCKS * 10) {
            float4 v = h2[r * 24 + q];
            acc.x += v.x; acc.y += v.y; acc.z += v.z; acc.w += v.w;
        }
    }
    __shared__ float4 sh[10][24];
    if (g < 10) sh[g][q] = acc;
    __syncthreads();
    if (threadIdx.x < 24) {
        float4 s = sh[0][threadIdx.x];
#pragma unroll
        for (int gg = 1; gg < 10; ++gg) {
            float4 v = sh[gg][threadIdx.x];
            s.x += v.x; s.y += v.y; s.z += v.z; s.w += v.w;
        }
        partials[blockIdx.x * 24 + threadIdx.x] = s;
    }
}

// ---------------- column-sum stage 2: 24 blocks, one float4 chunk each ----------------
__global__ __launch_bounds__(256) void reduce_partials(const float4* __restrict__ partials,
        float4* __restrict__ colsum, int nb) {
    int q = blockIdx.x;
    int t = threadIdx.x;
    float4 acc = {0.f, 0.f, 0.f, 0.f};
    for (int b = t; b < nb; b += 256) {
        float4 v = partials[b * 24 + q];
        acc.x += v.x; acc.y += v.y; acc.z += v.z; acc.w += v.w;
    }
    __shared__ float4 sh[256];
    sh[t] = acc;
    __syncthreads();
    for (int off = 128; off > 0; off >>= 1) {
        if (t < off) {
            sh[t].x += sh[t + off].x; sh[t].y += sh[t + off].y;
            sh[t].z += sh[t + off].z; sh[t].w += sh[t + off].w;
        }
        __syncthreads();
    }
    if (t == 0) colsum[q] = sh[0];
}

// ---------------- final MLP heads (single block) ----------------
__global__ __launch_bounds__(128) void head_kernel(const float* __restrict__ colsum, int n,
        const float* __restrict__ lin_w, const float* __restrict__ lin_b,
        const float* __restrict__ q_w, const float* __restrict__ q_b,
        const float* __restrict__ g_w, const float* __restrict__ g_b,
        const float* __restrict__ p_w, const float* __restrict__ p_b,
        const float* __restrict__ t_w, const float* __restrict__ t_b,
        float* __restrict__ out) {
    __shared__ float hm[96];
    __shared__ float h[96];
    int t = threadIdx.x;
    if (t < 96) hm[t] = colsum[t] / (float)n;
    __syncthreads();
    if (t < 96) {
        float s = lin_b[t];
        for (int k = 0; k < 96; ++k) s = fmaf(hm[k], lin_w[k * 96 + t], s);
        h[t] = fmaxf(s, 0.f);
    }
    __syncthreads();
    if (t < 43) {
        float s;
        if (t < 16) {
            s = q_b[t];
            for (int k = 0; k < 96; ++k) s = fmaf(h[k], q_w[k * 16 + t], s);
        } else if (t < 24) {
            int j = t - 16;
            s = g_b[j];
            for (int k = 0; k < 96; ++k) s = fmaf(h[k], g_w[k * 8 + j], s);
        } else if (t < 28) {
            int j = t - 24;
            s = p_b[j];
            for (int k = 0; k < 96; ++k) s = fmaf(h[k], p_w[k * 4 + j], s);
        } else {
            int j = t - 28;
            s = t_b[j];
            for (int k = 0; k < 96; ++k) s = fmaf(h[k], t_w[k * 15 + j], s);
        }
        out[t] = s;
    }
}

extern "C" void kernel_launch(void* const* d_in, const int* in_sizes, int n_in,
                              void* d_out, int out_size, void* d_ws, size_t ws_size,
                              hipStream_t stream) {
    const float* x     = (const float*)d_in[0];
    const int*   edges = (const int*)d_in[1];
    const float* W1    = (const float*)d_in[2];
    const float* b1    = (const float*)d_in[3];
    const float* W2    = (const float*)d_in[4];
    const float* b2    = (const float*)d_in[5];
    const float* lin_w = (const float*)d_in[6];
    const float* lin_b = (const float*)d_in[7];
    const float* q_w   = (const float*)d_in[8];
    const float* q_b   = (const float*)d_in[9];
    const float* g_w   = (const float*)d_in[10];
    const float* g_b   = (const float*)d_in[11];
    const float* p_w   = (const float*)d_in[12];
    const float* p_b   = (const float*)d_in[13];
    const float* t_w   = (const float*)d_in[14];
    const float* t_b   = (const float*)d_in[15];

    const int N = in_sizes[0] / HID;   // 50000
    const int E = in_sizes[1] / 2;     // 800000
    const int* src = edges;
    const int* dst = edges + E;

    char* w = (char*)d_ws;
    auto carve = [&](size_t bytes) {
        char* p = w;
        w += (bytes + 255) & ~size_t(255);
        return (void*)p;
    };
    float* hs        = (float*)carve((size_t)N * HID * 4);
    float* hbuf      = (float*)carve((size_t)N * HID * 4);
    float* dinv      = (float*)carve((size_t)N * 4);
    int*   cnt       = (int*)  carve((size_t)N * 4);
    int*   row_start = (int*)  carve((size_t)(N + 1) * 4);
    int*   cursor    = (int*)  carve((size_t)N * 4);
    int*   csr_src   = (int*)  carve((size_t)E * 4);
    float* partials  = (float*)carve((size_t)CS_BLOCKS * HID * 4);
    float* colsum    = (float*)carve((size_t)HID * 4);
    int*   blocksums = (int*)  carve((size_t)1024 * 4);

    const int elems_per_blk = SCAN_BLOCK * SCAN_CHUNK;          // 2048
    const int scan_blocks = (N + elems_per_blk - 1) / elems_per_blk;  // 25

    // CSR build + dinv
    hipMemsetAsync(cnt, 0, (size_t)N * 4, stream);
    hist_kernel<<<(E + 255) / 256, 256, 0, stream>>>(dst, cnt, E);
    scan_partial<<<scan_blocks, SCAN_BLOCK, 0, stream>>>(cnt, blocksums, N);
    scan_sums<<<1, 1024, 0, stream>>>(blocksums, scan_blocks);
    scan_expand<<<scan_blocks, SCAN_BLOCK, 0, stream>>>(cnt, blocksums, row_start,
                                                        cursor, dinv, N, E);
    scatter_kernel<<<(E + 255) / 256, 256, 0, stream>>>(src, dst, cursor, csr_src, E);

    int gemm_blocks = (N + 63) / 64;
    int gthreads = N * 24;

    // layer 1
    gemm_scale<<<gemm_blocks, 256, 0, stream>>>(x, W1, dinv, hs, N);
    gather_kernel<<<(gthreads + 255) / 256, 256, 0, stream>>>(
        (const float4*)hs, row_start, csr_src, dinv, b1, (float4*)hbuf, N);
    // layer 2
    gemm_scale<<<gemm_blocks, 256, 0, stream>>>(hbuf, W2, dinv, hs, N);
    gather_kernel<<<(gthreads + 255) / 256, 256, 0, stream>>>(
        (const float4*)hs, row_start, csr_src, dinv, b2, (float4*)hbuf, N);

    // pool + heads
    colsum_kernel<<<CS_BLOCKS, 256, 0, stream>>>((const float4*)hbuf, (float4*)partials, N);
    reduce_partials<<<24, 256, 0, stream>>>((const float4*)partials, (float4*)colsum, CS_BLOCKS);
    head_kernel<<<1, 128, 0, stream>>>(colsum, N, lin_w, lin_b,
        q_w, q_b, g_w, g_b, p_w, p_b, t_w, t_b, (float*)d_out);
}

// Round 4
// 257.124 us; speedup vs baseline: 1.9323x; 1.1796x over previous
//
#include <hip/hip_runtime.h>

#define HID 96
#define SCAN_BLOCK 256
#define SCAN_CHUNK 8   // elements per thread; 2048 per block
#define CS_BLOCKS 768  // colsum grid (3 per CU)

typedef unsigned int u32;
typedef unsigned short u16;

// ---- bf16 helpers (storage-only bf16; all math in f32) ----
__device__ __forceinline__ float bl(u32 u) { return __uint_as_float(u << 16); }          // low bf16
__device__ __forceinline__ float bh(u32 u) { return __uint_as_float(u & 0xFFFF0000u); }  // high bf16
__device__ __forceinline__ u16 f2bf(float f) {  // round-to-nearest-even
    u32 u = __float_as_uint(f);
    return (u16)((u + 0x7FFFu + ((u >> 16) & 1u)) >> 16);
}
__device__ __forceinline__ u32 packbf(float a, float b) {
    return (u32)f2bf(a) | ((u32)f2bf(b) << 16);
}

// ---------------- CSR build ----------------
__global__ void hist_kernel(const int* __restrict__ dst, int* __restrict__ cnt, int E) {
    int e = blockIdx.x * blockDim.x + threadIdx.x;
    if (e < E) atomicAdd(&cnt[dst[e]], 1);
}

__global__ __launch_bounds__(SCAN_BLOCK) void scan_partial(const int* __restrict__ cnt,
        int* __restrict__ blocksums, int n) {
    int base = (blockIdx.x * SCAN_BLOCK + threadIdx.x) * SCAN_CHUNK;
    int s = 0;
#pragma unroll
    for (int j = 0; j < SCAN_CHUNK; ++j) {
        int idx = base + j;
        if (idx < n) s += cnt[idx];
    }
    __shared__ int red[SCAN_BLOCK];
    red[threadIdx.x] = s;
    __syncthreads();
    for (int off = SCAN_BLOCK / 2; off > 0; off >>= 1) {
        if (threadIdx.x < off) red[threadIdx.x] += red[threadIdx.x + off];
        __syncthreads();
    }
    if (threadIdx.x == 0) blocksums[blockIdx.x] = red[0];
}

__global__ __launch_bounds__(1024) void scan_sums(int* __restrict__ blocksums, int nb) {
    __shared__ int sh[1024];
    int t = threadIdx.x;
    sh[t] = (t < nb) ? blocksums[t] : 0;
    __syncthreads();
    for (int off = 1; off < 1024; off <<= 1) {
        int v = (t >= off) ? sh[t - off] : 0;
        __syncthreads();
        sh[t] += v;
        __syncthreads();
    }
    if (t < nb) blocksums[t] = (t == 0) ? 0 : sh[t - 1];
}

__global__ __launch_bounds__(SCAN_BLOCK) void scan_expand(const int* __restrict__ cnt,
        const int* __restrict__ blocksums, int* __restrict__ row_start,
        int* __restrict__ cursor, float* __restrict__ dinv, int n, int E) {
    int t = threadIdx.x;
    int tbase = (blockIdx.x * SCAN_BLOCK + t) * SCAN_CHUNK;
    int local[SCAN_CHUNK];
    int s = 0;
#pragma unroll
    for (int j = 0; j < SCAN_CHUNK; ++j) {
        int idx = tbase + j;
        int c = (idx < n) ? cnt[idx] : 0;
        local[j] = c;
        s += c;
    }
    __shared__ int sh[SCAN_BLOCK];
    sh[t] = s;
    __syncthreads();
    for (int off = 1; off < SCAN_BLOCK; off <<= 1) {
        int v = (t >= off) ? sh[t - off] : 0;
        __syncthreads();
        sh[t] += v;
        __syncthreads();
    }
    int run = blocksums[blockIdx.x] + ((t == 0) ? 0 : sh[t - 1]);
#pragma unroll
    for (int j = 0; j < SCAN_CHUNK; ++j) {
        int idx = tbase + j;
        if (idx < n) {
            row_start[idx] = run;
            cursor[idx] = run;
            dinv[idx] = 1.0f / sqrtf((float)(local[j] + 1));  // +1 self-loop
            run += local[j];
        }
    }
    if (blockIdx.x == 0 && t == 0) row_start[n] = E;
}

__global__ void scatter_kernel(const int* __restrict__ src, const int* __restrict__ dst,
        int* __restrict__ cursor, int* __restrict__ csr_src, int E) {
    int e = blockIdx.x * blockDim.x + threadIdx.x;
    if (e < E) {
        int d = dst[e];
        int slot = atomicAdd(&cursor[d], 1);
        csr_src[slot] = src[e];
    }
}

// ---------------- dense GEMM: hs[i,:] = bf16(dinv[i] * (in[i,:] @ W)) ----------------
__device__ __forceinline__ float load_f32(const float* p) { return *p; }
__device__ __forceinline__ float load_f32(const u16* p) { return bl((u32)(*p)); }

template <typename TI>
__global__ __launch_bounds__(256) void gemm_scale(const TI* __restrict__ in,
        const float* __restrict__ W, const float* __restrict__ dinv,
        u16* __restrict__ out, int n) {
    __shared__ float Ws[96][96];
    __shared__ float Xs[64][98];
    int t = threadIdx.x;
    for (int idx = t; idx < 96 * 96; idx += 256) Ws[idx / 96][idx % 96] = W[idx];
    int row0 = blockIdx.x * 64;
    for (int idx = t; idx < 64 * 96; idx += 256) {
        int r = idx / 96, c = idx % 96;
        int gr = row0 + r;
        Xs[r][c] = (gr < n) ? load_f32(in + gr * 96 + c) : 0.f;
    }
    __syncthreads();
    int ty = t >> 4, tx = t & 15;
    float acc[4][6];
#pragma unroll
    for (int i = 0; i < 4; ++i)
#pragma unroll
        for (int j = 0; j < 6; ++j) acc[i][j] = 0.f;
#pragma unroll 4
    for (int k = 0; k < 96; ++k) {
        float xv[4], wv[6];
#pragma unroll
        for (int i = 0; i < 4; ++i) xv[i] = Xs[ty * 4 + i][k];
#pragma unroll
        for (int j = 0; j < 6; ++j) wv[j] = Ws[k][tx * 6 + j];
#pragma unroll
        for (int i = 0; i < 4; ++i)
#pragma unroll
            for (int j = 0; j < 6; ++j) acc[i][j] = fmaf(xv[i], wv[j], acc[i][j]);
    }
#pragma unroll
    for (int i = 0; i < 4; ++i) {
        int gr = row0 + ty * 4 + i;
        if (gr < n) {
            float dv = dinv[gr];
            u32* op = (u32*)(out + gr * 96 + tx * 6);  // byte off = 192*gr + 12*tx, 4B-aligned
            op[0] = packbf(dv * acc[i][0], dv * acc[i][1]);
            op[1] = packbf(dv * acc[i][2], dv * acc[i][3]);
            op[2] = packbf(dv * acc[i][4], dv * acc[i][5]);
        }
    }
}

// ---------------- gather aggregation + scale + bias + relu (bf16 rows) ----------------
// row = 96 bf16 = 192 B = 12 x uint4; thread per (node, 16B chunk)
__global__ void gather_kernel(const uint4* __restrict__ hs, const int* __restrict__ row_start,
        const int* __restrict__ csr_src, const float* __restrict__ dinv,
        const float* __restrict__ bias, uint4* __restrict__ out, int n) {
    int gid = blockIdx.x * blockDim.x + threadIdx.x;
    if (gid >= n * 12) return;
    int i = gid / 12, q = gid - i * 12;
    uint4 v = hs[i * 12 + q];   // self-loop term (pre-scaled by dinv[i])
    float acc[8] = { bl(v.x), bh(v.x), bl(v.y), bh(v.y),
                     bl(v.z), bh(v.z), bl(v.w), bh(v.w) };
    int e = row_start[i], e1 = row_start[i + 1];
    for (; e + 1 < e1; e += 2) {
        int s0 = csr_src[e], s1 = csr_src[e + 1];
        uint4 a = hs[s0 * 12 + q];
        uint4 b = hs[s1 * 12 + q];
        acc[0] += bl(a.x); acc[1] += bh(a.x); acc[2] += bl(a.y); acc[3] += bh(a.y);
        acc[4] += bl(a.z); acc[5] += bh(a.z); acc[6] += bl(a.w); acc[7] += bh(a.w);
        acc[0] += bl(b.x); acc[1] += bh(b.x); acc[2] += bl(b.y); acc[3] += bh(b.y);
        acc[4] += bl(b.z); acc[5] += bh(b.z); acc[6] += bl(b.w); acc[7] += bh(b.w);
    }
    if (e < e1) {
        int s0 = csr_src[e];
        uint4 a = hs[s0 * 12 + q];
        acc[0] += bl(a.x); acc[1] += bh(a.x); acc[2] += bl(a.y); acc[3] += bh(a.y);
        acc[4] += bl(a.z); acc[5] += bh(a.z); acc[6] += bl(a.w); acc[7] += bh(a.w);
    }
    float dv = dinv[i];
    const float4 b0 = reinterpret_cast<const float4*>(bias)[q * 2];
    const float4 b1 = reinterpret_cast<const float4*>(bias)[q * 2 + 1];
    float r0 = fmaxf(fmaf(acc[0], dv, b0.x), 0.f);
    float r1 = fmaxf(fmaf(acc[1], dv, b0.y), 0.f);
    float r2 = fmaxf(fmaf(acc[2], dv, b0.z), 0.f);
    float r3 = fmaxf(fmaf(acc[3], dv, b0.w), 0.f);
    float r4 = fmaxf(fmaf(acc[4], dv, b1.x), 0.f);
    float r5 = fmaxf(fmaf(acc[5], dv, b1.y), 0.f);
    float r6 = fmaxf(fmaf(acc[6], dv, b1.z), 0.f);
    float r7 = fmaxf(fmaf(acc[7], dv, b1.w), 0.f);
    uint4 o;
    o.x = packbf(r0, r1); o.y = packbf(r2, r3);
    o.z = packbf(r4, r5); o.w = packbf(r6, r7);
    out[i * 12 + q] = o;
}

// ---------------- column-sum of bf16 h2 [n x 96]: stage 1 ----------------
__global__ __launch_bounds__(256) void colsum_kernel(const uint4* __restrict__ h2,
        float* __restrict__ partials, int n) {
    int t = threadIdx.x;
    int q = t % 12, g = t / 12;  // g in 0..20 used (252 threads)
    float acc[8] = {0.f, 0.f, 0.f, 0.f, 0.f, 0.f, 0.f, 0.f};
    if (g < 21) {
        for (int r = blockIdx.x * 21 + g; r < n; r += CS_BLOCKS * 21) {
            uint4 v = h2[r * 12 + q];
            acc[0] += bl(v.x); acc[1] += bh(v.x); acc[2] += bl(v.y); acc[3] += bh(v.y);
            acc[4] += bl(v.z); acc[5] += bh(v.z); acc[6] += bl(v.w); acc[7] += bh(v.w);
        }
    }
    __shared__ float sh[21][96];
    if (g < 21) {
#pragma unroll
        for (int j = 0; j < 8; ++j) sh[g][q * 8 + j] = acc[j];
    }
    __syncthreads();
    if (t < 96) {
        float s = 0.f;
#pragma unroll
        for (int gg = 0; gg < 21; ++gg) s += sh[gg][t];
        partials[blockIdx.x * 96 + t] = s;
    }
}

// ---------------- column-sum stage 2: 24 blocks, one float4 chunk each ----------------
__global__ __launch_bounds__(256) void reduce_partials(const float4* __restrict__ partials,
        float4* __restrict__ colsum, int nb) {
    int q = blockIdx.x;
    int t = threadIdx.x;
    float4 acc = {0.f, 0.f, 0.f, 0.f};
    for (int b = t; b < nb; b += 256) {
        float4 v = partials[b * 24 + q];
        acc.x += v.x; acc.y += v.y; acc.z += v.z; acc.w += v.w;
    }
    __shared__ float4 sh[256];
    sh[t] = acc;
    __syncthreads();
    for (int off = 128; off > 0; off >>= 1) {
        if (t < off) {
            sh[t].x += sh[t + off].x; sh[t].y += sh[t + off].y;
            sh[t].z += sh[t + off].z; sh[t].w += sh[t + off].w;
        }
        __syncthreads();
    }
    if (t == 0) colsum[q] = sh[0];
}

// ---------------- final MLP heads (single block) ----------------
__global__ __launch_bounds__(128) void head_kernel(const float* __restrict__ colsum, int n,
        const float* __restrict__ lin_w, const float* __restrict__ lin_b,
        const float* __restrict__ q_w, const float* __restrict__ q_b,
        const float* __restrict__ g_w, const float* __restrict__ g_b,
        const float* __restrict__ p_w, const float* __restrict__ p_b,
        const float* __restrict__ t_w, const float* __restrict__ t_b,
        float* __restrict__ out) {
    __shared__ float hm[96];
    __shared__ float h[96];
    int t = threadIdx.x;
    if (t < 96) hm[t] = colsum[t] / (float)n;
    __syncthreads();
    if (t < 96) {
        float s = lin_b[t];
        for (int k = 0; k < 96; ++k) s = fmaf(hm[k], lin_w[k * 96 + t], s);
        h[t] = fmaxf(s, 0.f);
    }
    __syncthreads();
    if (t < 43) {
        float s;
        if (t < 16) {
            s = q_b[t];
            for (int k = 0; k < 96; ++k) s = fmaf(h[k], q_w[k * 16 + t], s);
        } else if (t < 24) {
            int j = t - 16;
            s = g_b[j];
            for (int k = 0; k < 96; ++k) s = fmaf(h[k], g_w[k * 8 + j], s);
        } else if (t < 28) {
            int j = t - 24;
            s = p_b[j];
            for (int k = 0; k < 96; ++k) s = fmaf(h[k], p_w[k * 4 + j], s);
        } else {
            int j = t - 28;
            s = t_b[j];
            for (int k = 0; k < 96; ++k) s = fmaf(h[k], t_w[k * 15 + j], s);
        }
        out[t] = s;
    }
}

extern "C" void kernel_launch(void* const* d_in, const int* in_sizes, int n_in,
                              void* d_out, int out_size, void* d_ws, size_t ws_size,
                              hipStream_t stream) {
    const float* x     = (const float*)d_in[0];
    const int*   edges = (const int*)d_in[1];
    const float* W1    = (const float*)d_in[2];
    const float* b1    = (const float*)d_in[3];
    const float* W2    = (const float*)d_in[4];
    const float* b2    = (const float*)d_in[5];
    const float* lin_w = (const float*)d_in[6];
    const float* lin_b = (const float*)d_in[7];
    const float* q_w   = (const float*)d_in[8];
    const float* q_b   = (const float*)d_in[9];
    const float* g_w   = (const float*)d_in[10];
    const float* g_b   = (const float*)d_in[11];
    const float* p_w   = (const float*)d_in[12];
    const float* p_b   = (const float*)d_in[13];
    const float* t_w   = (const float*)d_in[14];
    const float* t_b   = (const float*)d_in[15];

    const int N = in_sizes[0] / HID;   // 50000
    const int E = in_sizes[1] / 2;     // 800000
    const int* src = edges;
    const int* dst = edges + E;

    char* w = (char*)d_ws;
    auto carve = [&](size_t bytes) {
        char* p = w;
        w += (bytes + 255) & ~size_t(255);
        return (void*)p;
    };
    u16*   hs        = (u16*)  carve((size_t)N * HID * 2);   // bf16 features
    u16*   hbuf      = (u16*)  carve((size_t)N * HID * 2);   // bf16 features
    float* dinv      = (float*)carve((size_t)N * 4);
    int*   cnt       = (int*)  carve((size_t)N * 4);
    int*   row_start = (int*)  carve((size_t)(N + 1) * 4);
    int*   cursor    = (int*)  carve((size_t)N * 4);
    int*   csr_src   = (int*)  carve((size_t)E * 4);
    float* partials  = (float*)carve((size_t)CS_BLOCKS * HID * 4);
    float* colsum    = (float*)carve((size_t)HID * 4);
    int*   blocksums = (int*)  carve((size_t)1024 * 4);

    const int elems_per_blk = SCAN_BLOCK * SCAN_CHUNK;          // 2048
    const int scan_blocks = (N + elems_per_blk - 1) / elems_per_blk;  // 25

    // CSR build + dinv
    hipMemsetAsync(cnt, 0, (size_t)N * 4, stream);
    hist_kernel<<<(E + 255) / 256, 256, 0, stream>>>(dst, cnt, E);
    scan_partial<<<scan_blocks, SCAN_BLOCK, 0, stream>>>(cnt, blocksums, N);
    scan_sums<<<1, 1024, 0, stream>>>(blocksums, scan_blocks);
    scan_expand<<<scan_blocks, SCAN_BLOCK, 0, stream>>>(cnt, blocksums, row_start,
                                                        cursor, dinv, N, E);
    scatter_kernel<<<(E + 255) / 256, 256, 0, stream>>>(src, dst, cursor, csr_src, E);

    int gemm_blocks = (N + 63) / 64;
    int gthreads = N * 12;

    // layer 1
    gemm_scale<float><<<gemm_blocks, 256, 0, stream>>>(x, W1, dinv, hs, N);
    gather_kernel<<<(gthreads + 255) / 256, 256, 0, stream>>>(
        (const uint4*)hs, row_start, csr_src, dinv, b1, (uint4*)hbuf, N);
    // layer 2
    gemm_scale<u16><<<gemm_blocks, 256, 0, stream>>>(hbuf, W2, dinv, hs, N);
    gather_kernel<<<(gthreads + 255) / 256, 256, 0, stream>>>(
        (const uint4*)hs, row_start, csr_src, dinv, b2, (uint4*)hbuf, N);

    // pool + heads
    colsum_kernel<<<CS_BLOCKS, 256, 0, stream>>>((const uint4*)hbuf, partials, N);
    reduce_partials<<<24, 256, 0, stream>>>((const float4*)partials, (float4*)colsum, CS_BLOCKS);
    head_kernel<<<1, 128, 0, stream>>>(colsum, N, lin_w, lin_b,
        q_w, q_b, g_w, g_b, p_w, p_b, t_w, t_b, (float*)d_out);
}

// Round 5
// 208.724 us; speedup vs baseline: 2.3803x; 1.2319x over previous
//
#include <hip/hip_runtime.h>

#define HID 96
#define CS_BLOCKS 768   // colsum grid (3 per CU)
#define BIN_SHIFT 8     // 256 nodes per bin
#define AP_PER_T 16     // edges per thread in binappend
#define AP_CHUNK (256 * AP_PER_T)   // 4096 edges per WG

typedef unsigned int u32;
typedef unsigned short u16;

// ---- bf16 helpers (storage-only bf16; all math in f32) ----
__device__ __forceinline__ float bl(u32 u) { return __uint_as_float(u << 16); }          // low bf16
__device__ __forceinline__ float bh(u32 u) { return __uint_as_float(u & 0xFFFF0000u); }  // high bf16
__device__ __forceinline__ u16 f2bf(float f) {  // round-to-nearest-even
    u32 u = __float_as_uint(f);
    return (u16)((u + 0x7FFFu + ((u >> 16) & 1u)) >> 16);
}
__device__ __forceinline__ u32 packbf(float a, float b) {
    return (u32)f2bf(a) | ((u32)f2bf(b) << 16);
}

// ---------------- CSR build, bin-partitioned ----------------
// bins of 256 nodes; nb = ceil(n/256) <= 256

__global__ __launch_bounds__(256) void binhist_kernel(const int* __restrict__ dst,
        int* __restrict__ bincnt, int E, int nb) {
    __shared__ int h[256];
    int t = threadIdx.x;
    h[t] = 0;
    __syncthreads();
    for (int e = blockIdx.x * 256 + t; e < E; e += gridDim.x * 256)
        atomicAdd(&h[dst[e] >> BIN_SHIFT], 1);
    __syncthreads();
    if (t < nb && h[t]) atomicAdd(&bincnt[t], h[t]);
}

__global__ __launch_bounds__(256) void binscan_kernel(const int* __restrict__ bincnt,
        int* __restrict__ bin_start, int* __restrict__ bin_cursor, int nb, int E) {
    __shared__ int sh[256];
    int t = threadIdx.x;
    sh[t] = (t < nb) ? bincnt[t] : 0;
    __syncthreads();
    for (int off = 1; off < 256; off <<= 1) {
        int v = (t >= off) ? sh[t - off] : 0;
        __syncthreads();
        sh[t] += v;
        __syncthreads();
    }
    if (t < nb) {
        int s = (t == 0) ? 0 : sh[t - 1];
        bin_start[t] = s;
        bin_cursor[t] = s;
    }
    if (t == 0) bin_start[nb] = E;
}

// partition edges into bin-grouped staging runs (one contiguous run per WG x bin)
__global__ __launch_bounds__(256) void binappend_kernel(const int* __restrict__ src,
        const int* __restrict__ dst, int* __restrict__ bin_cursor,
        uint2* __restrict__ staging, int E) {
    __shared__ int cnt[256];
    __shared__ int pos[256];
    int t = threadIdx.x;
    cnt[t] = 0;
    __syncthreads();
    int base = blockIdx.x * AP_CHUNK + t;
    uint2 pr[AP_PER_T];
    int bn[AP_PER_T];
#pragma unroll
    for (int j = 0; j < AP_PER_T; ++j) {
        int e = base + j * 256;
        if (e < E) {
            pr[j].x = (u32)src[e];
            pr[j].y = (u32)dst[e];
            bn[j] = (int)(pr[j].y >> BIN_SHIFT);
            atomicAdd(&cnt[bn[j]], 1);
        } else bn[j] = -1;
    }
    __syncthreads();
    if (cnt[t]) pos[t] = atomicAdd(&bin_cursor[t], cnt[t]);
    __syncthreads();
#pragma unroll
    for (int j = 0; j < AP_PER_T; ++j) {
        if (bn[j] >= 0) {
            int p = atomicAdd(&pos[bn[j]], 1);
            staging[p] = pr[j];
        }
    }
}

// one WG per bin: node hist + scan (-> row_start, dinv) then local placement of csr_src
__global__ __launch_bounds__(256) void binplace_kernel(const uint2* __restrict__ staging,
        const int* __restrict__ bin_start, int* __restrict__ row_start,
        float* __restrict__ dinv, int* __restrict__ csr_src, int n, int E, int nb) {
    __shared__ int ncnt[256];
    __shared__ int sh[256];
    __shared__ int nstart[256];
    int b = blockIdx.x;
    int t = threadIdx.x;
    int nbase = b << BIN_SHIFT;
    int nnodes = min(256, n - nbase);
    int s0 = bin_start[b], s1 = bin_start[b + 1];
    ncnt[t] = 0;
    __syncthreads();
    for (int e = s0 + t; e < s1; e += 256)
        atomicAdd(&ncnt[(int)staging[e].y - nbase], 1);
    __syncthreads();
    int v0 = ncnt[t];
    sh[t] = v0;
    __syncthreads();
    for (int off = 1; off < 256; off <<= 1) {
        int v = (t >= off) ? sh[t - off] : 0;
        __syncthreads();
        sh[t] += v;
        __syncthreads();
    }
    int mystart = s0 + sh[t] - v0;   // exclusive prefix
    if (t < nnodes) {
        row_start[nbase + t] = mystart;
        dinv[nbase + t] = 1.0f / sqrtf((float)(v0 + 1));  // +1 self-loop
        nstart[t] = mystart;
    }
    if (b == nb - 1 && t == 0) row_start[n] = E;
    __syncthreads();
    for (int e = s0 + t; e < s1; e += 256) {
        uint2 pr = staging[e];
        int slot = atomicAdd(&nstart[(int)pr.y - nbase], 1);
        csr_src[slot] = (int)pr.x;
    }
}

// ---------------- dense GEMM: hs[i,:] = bf16(dinv[i] * (in[i,:] @ W)) ----------------
__device__ __forceinline__ float load_f32(const float* p) { return *p; }
__device__ __forceinline__ float load_f32(const u16* p) { return bl((u32)(*p)); }

template <typename TI>
__global__ __launch_bounds__(256) void gemm_scale(const TI* __restrict__ in,
        const float* __restrict__ W, const float* __restrict__ dinv,
        u16* __restrict__ out, int n) {
    __shared__ float Ws[96][96];
    __shared__ float Xs[64][98];
    int t = threadIdx.x;
    for (int idx = t; idx < 96 * 96; idx += 256) Ws[idx / 96][idx % 96] = W[idx];
    int row0 = blockIdx.x * 64;
    for (int idx = t; idx < 64 * 96; idx += 256) {
        int r = idx / 96, c = idx % 96;
        int gr = row0 + r;
        Xs[r][c] = (gr < n) ? load_f32(in + gr * 96 + c) : 0.f;
    }
    __syncthreads();
    int ty = t >> 4, tx = t & 15;
    float acc[4][6];
#pragma unroll
    for (int i = 0; i < 4; ++i)
#pragma unroll
        for (int j = 0; j < 6; ++j) acc[i][j] = 0.f;
#pragma unroll 4
    for (int k = 0; k < 96; ++k) {
        float xv[4], wv[6];
#pragma unroll
        for (int i = 0; i < 4; ++i) xv[i] = Xs[ty * 4 + i][k];
#pragma unroll
        for (int j = 0; j < 6; ++j) wv[j] = Ws[k][tx * 6 + j];
#pragma unroll
        for (int i = 0; i < 4; ++i)
#pragma unroll
            for (int j = 0; j < 6; ++j) acc[i][j] = fmaf(xv[i], wv[j], acc[i][j]);
    }
#pragma unroll
    for (int i = 0; i < 4; ++i) {
        int gr = row0 + ty * 4 + i;
        if (gr < n) {
            float dv = dinv[gr];
            u32* op = (u32*)(out + gr * 96 + tx * 6);
            op[0] = packbf(dv * acc[i][0], dv * acc[i][1]);
            op[1] = packbf(dv * acc[i][2], dv * acc[i][3]);
            op[2] = packbf(dv * acc[i][4], dv * acc[i][5]);
        }
    }
}

// ---------------- gather aggregation + scale + bias + relu (bf16 rows) ----------------
__global__ void gather_kernel(const uint4* __restrict__ hs, const int* __restrict__ row_start,
        const int* __restrict__ csr_src, const float* __restrict__ dinv,
        const float* __restrict__ bias, uint4* __restrict__ out, int n) {
    int gid = blockIdx.x * blockDim.x + threadIdx.x;
    if (gid >= n * 12) return;
    int i = gid / 12, q = gid - i * 12;
    uint4 v = hs[i * 12 + q];   // self-loop term (pre-scaled by dinv[i])
    float acc[8] = { bl(v.x), bh(v.x), bl(v.y), bh(v.y),
                     bl(v.z), bh(v.z), bl(v.w), bh(v.w) };
    int e = row_start[i], e1 = row_start[i + 1];
    for (; e + 1 < e1; e += 2) {
        int s0 = csr_src[e], s1 = csr_src[e + 1];
        uint4 a = hs[s0 * 12 + q];
        uint4 b = hs[s1 * 12 + q];
        acc[0] += bl(a.x); acc[1] += bh(a.x); acc[2] += bl(a.y); acc[3] += bh(a.y);
        acc[4] += bl(a.z); acc[5] += bh(a.z); acc[6] += bl(a.w); acc[7] += bh(a.w);
        acc[0] += bl(b.x); acc[1] += bh(b.x); acc[2] += bl(b.y); acc[3] += bh(b.y);
        acc[4] += bl(b.z); acc[5] += bh(b.z); acc[6] += bl(b.w); acc[7] += bh(b.w);
    }
    if (e < e1) {
        int s0 = csr_src[e];
        uint4 a = hs[s0 * 12 + q];
        acc[0] += bl(a.x); acc[1] += bh(a.x); acc[2] += bl(a.y); acc[3] += bh(a.y);
        acc[4] += bl(a.z); acc[5] += bh(a.z); acc[6] += bl(a.w); acc[7] += bh(a.w);
    }
    float dv = dinv[i];
    const float4 b0 = reinterpret_cast<const float4*>(bias)[q * 2];
    const float4 b1 = reinterpret_cast<const float4*>(bias)[q * 2 + 1];
    float r0 = fmaxf(fmaf(acc[0], dv, b0.x), 0.f);
    float r1 = fmaxf(fmaf(acc[1], dv, b0.y), 0.f);
    float r2 = fmaxf(fmaf(acc[2], dv, b0.z), 0.f);
    float r3 = fmaxf(fmaf(acc[3], dv, b0.w), 0.f);
    float r4 = fmaxf(fmaf(acc[4], dv, b1.x), 0.f);
    float r5 = fmaxf(fmaf(acc[5], dv, b1.y), 0.f);
    float r6 = fmaxf(fmaf(acc[6], dv, b1.z), 0.f);
    float r7 = fmaxf(fmaf(acc[7], dv, b1.w), 0.f);
    uint4 o;
    o.x = packbf(r0, r1); o.y = packbf(r2, r3);
    o.z = packbf(r4, r5); o.w = packbf(r6, r7);
    out[i * 12 + q] = o;
}

// ---------------- column-sum of bf16 h2 [n x 96]: stage 1 ----------------
__global__ __launch_bounds__(256) void colsum_kernel(const uint4* __restrict__ h2,
        float* __restrict__ partials, int n) {
    int t = threadIdx.x;
    int q = t % 12, g = t / 12;  // g in 0..20 used (252 threads)
    float acc[8] = {0.f, 0.f, 0.f, 0.f, 0.f, 0.f, 0.f, 0.f};
    if (g < 21) {
        for (int r = blockIdx.x * 21 + g; r < n; r += CS_BLOCKS * 21) {
            uint4 v = h2[r * 12 + q];
            acc[0] += bl(v.x); acc[1] += bh(v.x); acc[2] += bl(v.y); acc[3] += bh(v.y);
            acc[4] += bl(v.z); acc[5] += bh(v.z); acc[6] += bl(v.w); acc[7] += bh(v.w);
        }
    }
    __shared__ float sh[21][96];
    if (g < 21) {
#pragma unroll
        for (int j = 0; j < 8; ++j) sh[g][q * 8 + j] = acc[j];
    }
    __syncthreads();
    if (t < 96) {
        float s = 0.f;
#pragma unroll
        for (int gg = 0; gg < 21; ++gg) s += sh[gg][t];
        partials[blockIdx.x * 96 + t] = s;
    }
}

// ---------------- column-sum stage 2 ----------------
__global__ __launch_bounds__(256) void reduce_partials(const float4* __restrict__ partials,
        float4* __restrict__ colsum, int nb) {
    int q = blockIdx.x;
    int t = threadIdx.x;
    float4 acc = {0.f, 0.f, 0.f, 0.f};
    for (int b = t; b < nb; b += 256) {
        float4 v = partials[b * 24 + q];
        acc.x += v.x; acc.y += v.y; acc.z += v.z; acc.w += v.w;
    }
    __shared__ float4 sh[256];
    sh[t] = acc;
    __syncthreads();
    for (int off = 128; off > 0; off >>= 1) {
        if (t < off) {
            sh[t].x += sh[t + off].x; sh[t].y += sh[t + off].y;
            sh[t].z += sh[t + off].z; sh[t].w += sh[t + off].w;
        }
        __syncthreads();
    }
    if (t == 0) colsum[q] = sh[0];
}

// ---------------- final MLP heads (single block) ----------------
__global__ __launch_bounds__(128) void head_kernel(const float* __restrict__ colsum, int n,
        const float* __restrict__ lin_w, const float* __restrict__ lin_b,
        const float* __restrict__ q_w, const float* __restrict__ q_b,
        const float* __restrict__ g_w, const float* __restrict__ g_b,
        const float* __restrict__ p_w, const float* __restrict__ p_b,
        const float* __restrict__ t_w, const float* __restrict__ t_b,
        float* __restrict__ out) {
    __shared__ float hm[96];
    __shared__ float h[96];
    int t = threadIdx.x;
    if (t < 96) hm[t] = colsum[t] / (float)n;
    __syncthreads();
    if (t < 96) {
        float s = lin_b[t];
        for (int k = 0; k < 96; ++k) s = fmaf(hm[k], lin_w[k * 96 + t], s);
        h[t] = fmaxf(s, 0.f);
    }
    __syncthreads();
    if (t < 43) {
        float s;
        if (t < 16) {
            s = q_b[t];
            for (int k = 0; k < 96; ++k) s = fmaf(h[k], q_w[k * 16 + t], s);
        } else if (t < 24) {
            int j = t - 16;
            s = g_b[j];
            for (int k = 0; k < 96; ++k) s = fmaf(h[k], g_w[k * 8 + j], s);
        } else if (t < 28) {
            int j = t - 24;
            s = p_b[j];
            for (int k = 0; k < 96; ++k) s = fmaf(h[k], p_w[k * 4 + j], s);
        } else {
            int j = t - 28;
            s = t_b[j];
            for (int k = 0; k < 96; ++k) s = fmaf(h[k], t_w[k * 15 + j], s);
        }
        out[t] = s;
    }
}

extern "C" void kernel_launch(void* const* d_in, const int* in_sizes, int n_in,
                              void* d_out, int out_size, void* d_ws, size_t ws_size,
                              hipStream_t stream) {
    const float* x     = (const float*)d_in[0];
    const int*   edges = (const int*)d_in[1];
    const float* W1    = (const float*)d_in[2];
    const float* b1    = (const float*)d_in[3];
    const float* W2    = (const float*)d_in[4];
    const float* b2    = (const float*)d_in[5];
    const float* lin_w = (const float*)d_in[6];
    const float* lin_b = (const float*)d_in[7];
    const float* q_w   = (const float*)d_in[8];
    const float* q_b   = (const float*)d_in[9];
    const float* g_w   = (const float*)d_in[10];
    const float* g_b   = (const float*)d_in[11];
    const float* p_w   = (const float*)d_in[12];
    const float* p_b   = (const float*)d_in[13];
    const float* t_w   = (const float*)d_in[14];
    const float* t_b   = (const float*)d_in[15];

    const int N = in_sizes[0] / HID;   // 50000
    const int E = in_sizes[1] / 2;     // 800000
    const int* src = edges;
    const int* dst = edges + E;
    const int NB = (N + 255) >> BIN_SHIFT;   // 196

    char* w = (char*)d_ws;
    auto carve = [&](size_t bytes) {
        char* p = w;
        w += (bytes + 255) & ~size_t(255);
        return (void*)p;
    };
    u16*   hs        = (u16*)  carve((size_t)N * HID * 2);
    u16*   hbuf      = (u16*)  carve((size_t)N * HID * 2);
    float* dinv      = (float*)carve((size_t)N * 4);
    int*   row_start = (int*)  carve((size_t)(N + 1) * 4);
    int*   csr_src   = (int*)  carve((size_t)E * 4);
    uint2* staging   = (uint2*)carve((size_t)E * 8);
    int*   bincnt    = (int*)  carve(256 * 4);
    int*   bin_start = (int*)  carve(257 * 4);
    int*   bin_cursor= (int*)  carve(256 * 4);
    float* partials  = (float*)carve((size_t)CS_BLOCKS * HID * 4);
    float* colsum    = (float*)carve((size_t)HID * 4);

    // CSR build (bin-partitioned counting sort) + row_start + dinv
    hipMemsetAsync(bincnt, 0, 256 * 4, stream);
    binhist_kernel<<<1024, 256, 0, stream>>>(dst, bincnt, E, NB);
    binscan_kernel<<<1, 256, 0, stream>>>(bincnt, bin_start, bin_cursor, NB, E);
    binappend_kernel<<<(E + AP_CHUNK - 1) / AP_CHUNK, 256, 0, stream>>>(
        src, dst, bin_cursor, staging, E);
    binplace_kernel<<<NB, 256, 0, stream>>>(staging, bin_start, row_start,
                                            dinv, csr_src, N, E, NB);

    int gemm_blocks = (N + 63) / 64;
    int gthreads = N * 12;

    // layer 1
    gemm_scale<float><<<gemm_blocks, 256, 0, stream>>>(x, W1, dinv, hs, N);
    gather_kernel<<<(gthreads + 255) / 256, 256, 0, stream>>>(
        (const uint4*)hs, row_start, csr_src, dinv, b1, (uint4*)hbuf, N);
    // layer 2
    gemm_scale<u16><<<gemm_blocks, 256, 0, stream>>>(hbuf, W2, dinv, hs, N);
    gather_kernel<<<(gthreads + 255) / 256, 256, 0, stream>>>(
        (const uint4*)hs, row_start, csr_src, dinv, b2, (uint4*)hbuf, N);

    // pool + heads
    colsum_kernel<<<CS_BLOCKS, 256, 0, stream>>>((const uint4*)hbuf, partials, N);
    reduce_partials<<<24, 256, 0, stream>>>((const float4*)partials, (float4*)colsum, CS_BLOCKS);
    head_kernel<<<1, 128, 0, stream>>>(colsum, N, lin_w, lin_b,
        q_w, q_b, g_w, g_b, p_w, p_b, t_w, t_b, (float*)d_out);
}

// Round 6
// 158.807 us; speedup vs baseline: 3.1285x; 1.3143x over previous
//
#include <hip/hip_runtime.h>

#define HID 96
#define CS_BLOCKS 768   // colsum grid (3 per CU)
#define BIN_SHIFT 8     // 256 nodes per bin
#define AP_PER_T 16     // edges per thread in binappend
#define AP_CHUNK (256 * AP_PER_T)   // 4096 edges per WG

typedef unsigned int u32;
typedef unsigned short u16;
typedef __attribute__((ext_vector_type(8))) short bf16x8;
typedef __attribute__((ext_vector_type(4))) float f32x4;

// ---- bf16 helpers (storage-only bf16; all math in f32) ----
__device__ __forceinline__ float bl(u32 u) { return __uint_as_float(u << 16); }          // low bf16
__device__ __forceinline__ float bh(u32 u) { return __uint_as_float(u & 0xFFFF0000u); }  // high bf16
__device__ __forceinline__ u16 f2bf(float f) {  // round-to-nearest-even
    u32 u = __float_as_uint(f);
    return (u16)((u + 0x7FFFu + ((u >> 16) & 1u)) >> 16);
}
__device__ __forceinline__ u32 packbf(float a, float b) {
    return (u32)f2bf(a) | ((u32)f2bf(b) << 16);
}

// ---------------- CSR build, bin-partitioned ----------------

__global__ __launch_bounds__(256) void binhist_kernel(const int* __restrict__ dst,
        int* __restrict__ bincnt, int E, int nb) {
    __shared__ int h[256];
    int t = threadIdx.x;
    h[t] = 0;
    __syncthreads();
    for (int e = blockIdx.x * 256 + t; e < E; e += gridDim.x * 256)
        atomicAdd(&h[dst[e] >> BIN_SHIFT], 1);
    __syncthreads();
    if (t < nb && h[t]) atomicAdd(&bincnt[t], h[t]);
}

__global__ __launch_bounds__(256) void binscan_kernel(const int* __restrict__ bincnt,
        int* __restrict__ bin_start, int* __restrict__ bin_cursor, int nb, int E) {
    __shared__ int sh[256];
    int t = threadIdx.x;
    sh[t] = (t < nb) ? bincnt[t] : 0;
    __syncthreads();
    for (int off = 1; off < 256; off <<= 1) {
        int v = (t >= off) ? sh[t - off] : 0;
        __syncthreads();
        sh[t] += v;
        __syncthreads();
    }
    if (t < nb) {
        int s = (t == 0) ? 0 : sh[t - 1];
        bin_start[t] = s;
        bin_cursor[t] = s;
    }
    if (t == 0) bin_start[nb] = E;
}

__global__ __launch_bounds__(256) void binappend_kernel(const int* __restrict__ src,
        const int* __restrict__ dst, int* __restrict__ bin_cursor,
        uint2* __restrict__ staging, int E) {
    __shared__ int cnt[256];
    __shared__ int pos[256];
    int t = threadIdx.x;
    cnt[t] = 0;
    __syncthreads();
    int base = blockIdx.x * AP_CHUNK + t;
    uint2 pr[AP_PER_T];
    int bn[AP_PER_T];
#pragma unroll
    for (int j = 0; j < AP_PER_T; ++j) {
        int e = base + j * 256;
        if (e < E) {
            pr[j].x = (u32)src[e];
            pr[j].y = (u32)dst[e];
            bn[j] = (int)(pr[j].y >> BIN_SHIFT);
            atomicAdd(&cnt[bn[j]], 1);
        } else bn[j] = -1;
    }
    __syncthreads();
    if (cnt[t]) pos[t] = atomicAdd(&bin_cursor[t], cnt[t]);
    __syncthreads();
#pragma unroll
    for (int j = 0; j < AP_PER_T; ++j) {
        if (bn[j] >= 0) {
            int p = atomicAdd(&pos[bn[j]], 1);
            staging[p] = pr[j];
        }
    }
}

__global__ __launch_bounds__(256) void binplace_kernel(const uint2* __restrict__ staging,
        const int* __restrict__ bin_start, int* __restrict__ row_start,
        float* __restrict__ dinv, int* __restrict__ csr_src, int n, int E, int nb) {
    __shared__ int ncnt[256];
    __shared__ int sh[256];
    __shared__ int nstart[256];
    int b = blockIdx.x;
    int t = threadIdx.x;
    int nbase = b << BIN_SHIFT;
    int nnodes = min(256, n - nbase);
    int s0 = bin_start[b], s1 = bin_start[b + 1];
    ncnt[t] = 0;
    __syncthreads();
    for (int e = s0 + t; e < s1; e += 256)
        atomicAdd(&ncnt[(int)staging[e].y - nbase], 1);
    __syncthreads();
    int v0 = ncnt[t];
    sh[t] = v0;
    __syncthreads();
    for (int off = 1; off < 256; off <<= 1) {
        int v = (t >= off) ? sh[t - off] : 0;
        __syncthreads();
        sh[t] += v;
        __syncthreads();
    }
    int mystart = s0 + sh[t] - v0;   // exclusive prefix
    if (t < nnodes) {
        row_start[nbase + t] = mystart;
        dinv[nbase + t] = 1.0f / sqrtf((float)(v0 + 1));  // +1 self-loop
        nstart[t] = mystart;
    }
    if (b == nb - 1 && t == 0) row_start[n] = E;
    __syncthreads();
    for (int e = s0 + t; e < s1; e += 256) {
        uint2 pr = staging[e];
        int slot = atomicAdd(&nstart[(int)pr.y - nbase], 1);
        csr_src[slot] = (int)pr.x;
    }
}

// ---------------- converts ----------------
// f32 -> bf16, 4 elements/thread
__global__ void convert_bf16(const float4* __restrict__ in, uint2* __restrict__ out, int n4) {
    int i = blockIdx.x * blockDim.x + threadIdx.x;
    if (i < n4) {
        float4 v = in[i];
        uint2 o;
        o.x = packbf(v.x, v.y);
        o.y = packbf(v.z, v.w);
        out[i] = o;
    }
}

// W[k*96+col] f32 -> wt[col*96+k] bf16 (transpose)
__global__ __launch_bounds__(256) void convert_wt(const float* __restrict__ W,
        u16* __restrict__ wt) {
    int idx = blockIdx.x * 256 + threadIdx.x;
    if (idx < 96 * 96) {
        int col = idx / 96, k = idx - col * 96;
        wt[idx] = f2bf(W[k * 96 + col]);
    }
}

// ---------------- MFMA GEMM: hs[i,:] = bf16(dinv[i] * (xb[i,:] @ W)) ----------------
// xb: [n x 96] bf16 row-major; wt: [96 x 96] bf16 transposed (wt[col*96+k]).
// 4 waves/block, 16 rows/wave, 64 rows/block. 18 MFMA (6 N-tiles x 3 K-steps) per wave.
__global__ __launch_bounds__(256) void gemm_mfma(const u16* __restrict__ xb,
        const u16* __restrict__ wt, const float* __restrict__ dinv,
        u16* __restrict__ out, int n) {
    __shared__ uint4 Wt4[96 * 13];   // 96 rows x 104 bf16 (208 B = 13 uint4), padded
    int t = threadIdx.x;
    const uint4* wsrc = (const uint4*)wt;
    for (int idx = t; idx < 96 * 12; idx += 256) {
        int row = idx / 12, c = idx - row * 12;
        Wt4[row * 13 + c] = wsrc[idx];
    }
    __syncthreads();

    int wave = t >> 6, lane = t & 63;
    int row0 = blockIdx.x * 64 + wave * 16;
    int kb = lane >> 4;              // 0..3 (k-block)
    int rc = lane & 15;              // row (A) / col (B,C) within tile
    int arow = row0 + rc;
    int ar = (arow < n) ? arow : 0;  // clamp OOB loads (stores guarded below)

    // A fragments: lane reads 8 consecutive bf16 at k = kk*32 + kb*8
    const uint4* ap = (const uint4*)(xb + (size_t)ar * 96);
    bf16x8 a0 = *(const bf16x8*)(ap + 0 * 4 + kb);
    bf16x8 a1 = *(const bf16x8*)(ap + 1 * 4 + kb);
    bf16x8 a2 = *(const bf16x8*)(ap + 2 * 4 + kb);

    const u16* wbase = (const u16*)Wt4;
    f32x4 acc[6];
#pragma unroll
    for (int j = 0; j < 6; ++j) acc[j] = (f32x4){0.f, 0.f, 0.f, 0.f};

#pragma unroll
    for (int j = 0; j < 6; ++j) {
        int col = j * 16 + rc;
        const u16* wp = wbase + col * 104 + kb * 8;
        bf16x8 b0 = *(const bf16x8*)(wp);
        bf16x8 b1 = *(const bf16x8*)(wp + 32);
        bf16x8 b2 = *(const bf16x8*)(wp + 64);
        acc[j] = __builtin_amdgcn_mfma_f32_16x16x32_bf16(a0, b0, acc[j], 0, 0, 0);
        acc[j] = __builtin_amdgcn_mfma_f32_16x16x32_bf16(a1, b1, acc[j], 0, 0, 0);
        acc[j] = __builtin_amdgcn_mfma_f32_16x16x32_bf16(a2, b2, acc[j], 0, 0, 0);
    }

    // C/D layout: col = rc, row = kb*4 + r  [m89-verified]
#pragma unroll
    for (int r = 0; r < 4; ++r) {
        int row = row0 + kb * 4 + r;
        if (row < n) {
            float dv = dinv[row];
            u16* orow = out + (size_t)row * 96 + rc;
#pragma unroll
            for (int j = 0; j < 6; ++j)
                orow[j * 16] = f2bf(dv * acc[j][r]);
        }
    }
}

// ---------------- gather aggregation + scale + bias + relu (bf16 rows) ----------------
__global__ void gather_kernel(const uint4* __restrict__ hs, const int* __restrict__ row_start,
        const int* __restrict__ csr_src, const float* __restrict__ dinv,
        const float* __restrict__ bias, uint4* __restrict__ out, int n) {
    int gid = blockIdx.x * blockDim.x + threadIdx.x;
    if (gid >= n * 12) return;
    int i = gid / 12, q = gid - i * 12;
    uint4 v = hs[i * 12 + q];   // self-loop term (pre-scaled by dinv[i])
    float acc[8] = { bl(v.x), bh(v.x), bl(v.y), bh(v.y),
                     bl(v.z), bh(v.z), bl(v.w), bh(v.w) };
    int e = row_start[i], e1 = row_start[i + 1];
    for (; e + 1 < e1; e += 2) {
        int s0 = csr_src[e], s1 = csr_src[e + 1];
        uint4 a = hs[s0 * 12 + q];
        uint4 b = hs[s1 * 12 + q];
        acc[0] += bl(a.x); acc[1] += bh(a.x); acc[2] += bl(a.y); acc[3] += bh(a.y);
        acc[4] += bl(a.z); acc[5] += bh(a.z); acc[6] += bl(a.w); acc[7] += bh(a.w);
        acc[0] += bl(b.x); acc[1] += bh(b.x); acc[2] += bl(b.y); acc[3] += bh(b.y);
        acc[4] += bl(b.z); acc[5] += bh(b.z); acc[6] += bl(b.w); acc[7] += bh(b.w);
    }
    if (e < e1) {
        int s0 = csr_src[e];
        uint4 a = hs[s0 * 12 + q];
        acc[0] += bl(a.x); acc[1] += bh(a.x); acc[2] += bl(a.y); acc[3] += bh(a.y);
        acc[4] += bl(a.z); acc[5] += bh(a.z); acc[6] += bl(a.w); acc[7] += bh(a.w);
    }
    float dv = dinv[i];
    const float4 b0 = reinterpret_cast<const float4*>(bias)[q * 2];
    const float4 b1 = reinterpret_cast<const float4*>(bias)[q * 2 + 1];
    float r0 = fmaxf(fmaf(acc[0], dv, b0.x), 0.f);
    float r1 = fmaxf(fmaf(acc[1], dv, b0.y), 0.f);
    float r2 = fmaxf(fmaf(acc[2], dv, b0.z), 0.f);
    float r3 = fmaxf(fmaf(acc[3], dv, b0.w), 0.f);
    float r4 = fmaxf(fmaf(acc[4], dv, b1.x), 0.f);
    float r5 = fmaxf(fmaf(acc[5], dv, b1.y), 0.f);
    float r6 = fmaxf(fmaf(acc[6], dv, b1.z), 0.f);
    float r7 = fmaxf(fmaf(acc[7], dv, b1.w), 0.f);
    uint4 o;
    o.x = packbf(r0, r1); o.y = packbf(r2, r3);
    o.z = packbf(r4, r5); o.w = packbf(r6, r7);
    out[i * 12 + q] = o;
}

// ---------------- column-sum of bf16 h2 [n x 96]: stage 1 ----------------
__global__ __launch_bounds__(256) void colsum_kernel(const uint4* __restrict__ h2,
        float* __restrict__ partials, int n) {
    int t = threadIdx.x;
    int q = t % 12, g = t / 12;  // g in 0..20 used (252 threads)
    float acc[8] = {0.f, 0.f, 0.f, 0.f, 0.f, 0.f, 0.f, 0.f};
    if (g < 21) {
        for (int r = blockIdx.x * 21 + g; r < n; r += CS_BLOCKS * 21) {
            uint4 v = h2[r * 12 + q];
            acc[0] += bl(v.x); acc[1] += bh(v.x); acc[2] += bl(v.y); acc[3] += bh(v.y);
            acc[4] += bl(v.z); acc[5] += bh(v.z); acc[6] += bl(v.w); acc[7] += bh(v.w);
        }
    }
    __shared__ float sh[21][96];
    if (g < 21) {
#pragma unroll
        for (int j = 0; j < 8; ++j) sh[g][q * 8 + j] = acc[j];
    }
    __syncthreads();
    if (t < 96) {
        float s = 0.f;
#pragma unroll
        for (int gg = 0; gg < 21; ++gg) s += sh[gg][t];
        partials[blockIdx.x * 96 + t] = s;
    }
}

// ---------------- column-sum stage 2 ----------------
__global__ __launch_bounds__(256) void reduce_partials(const float4* __restrict__ partials,
        float4* __restrict__ colsum, int nb) {
    int q = blockIdx.x;
    int t = threadIdx.x;
    float4 acc = {0.f, 0.f, 0.f, 0.f};
    for (int b = t; b < nb; b += 256) {
        float4 v = partials[b * 24 + q];
        acc.x += v.x; acc.y += v.y; acc.z += v.z; acc.w += v.w;
    }
    __shared__ float4 sh[256];
    sh[t] = acc;
    __syncthreads();
    for (int off = 128; off > 0; off >>= 1) {
        if (t < off) {
            sh[t].x += sh[t + off].x; sh[t].y += sh[t + off].y;
            sh[t].z += sh[t + off].z; sh[t].w += sh[t + off].w;
        }
        __syncthreads();
    }
    if (t == 0) colsum[q] = sh[0];
}

// ---------------- final MLP heads (single block) ----------------
__global__ __launch_bounds__(128) void head_kernel(const float* __restrict__ colsum, int n,
        const float* __restrict__ lin_w, const float* __restrict__ lin_b,
        const float* __restrict__ q_w, const float* __restrict__ q_b,
        const float* __restrict__ g_w, const float* __restrict__ g_b,
        const float* __restrict__ p_w, const float* __restrict__ p_b,
        const float* __restrict__ t_w, const float* __restrict__ t_b,
        float* __restrict__ out) {
    __shared__ float hm[96];
    __shared__ float h[96];
    int t = threadIdx.x;
    if (t < 96) hm[t] = colsum[t] / (float)n;
    __syncthreads();
    if (t < 96) {
        float s = lin_b[t];
        for (int k = 0; k < 96; ++k) s = fmaf(hm[k], lin_w[k * 96 + t], s);
        h[t] = fmaxf(s, 0.f);
    }
    __syncthreads();
    if (t < 43) {
        float s;
        if (t < 16) {
            s = q_b[t];
            for (int k = 0; k < 96; ++k) s = fmaf(h[k], q_w[k * 16 + t], s);
        } else if (t < 24) {
            int j = t - 16;
            s = g_b[j];
            for (int k = 0; k < 96; ++k) s = fmaf(h[k], g_w[k * 8 + j], s);
        } else if (t < 28) {
            int j = t - 24;
            s = p_b[j];
            for (int k = 0; k < 96; ++k) s = fmaf(h[k], p_w[k * 4 + j], s);
        } else {
            int j = t - 28;
            s = t_b[j];
            for (int k = 0; k < 96; ++k) s = fmaf(h[k], t_w[k * 15 + j], s);
        }
        out[t] = s;
    }
}

extern "C" void kernel_launch(void* const* d_in, const int* in_sizes, int n_in,
                              void* d_out, int out_size, void* d_ws, size_t ws_size,
                              hipStream_t stream) {
    const float* x     = (const float*)d_in[0];
    const int*   edges = (const int*)d_in[1];
    const float* W1    = (const float*)d_in[2];
    const float* b1    = (const float*)d_in[3];
    const float* W2    = (const float*)d_in[4];
    const float* b2    = (const float*)d_in[5];
    const float* lin_w = (const float*)d_in[6];
    const float* lin_b = (const float*)d_in[7];
    const float* q_w   = (const float*)d_in[8];
    const float* q_b   = (const float*)d_in[9];
    const float* g_w   = (const float*)d_in[10];
    const float* g_b   = (const float*)d_in[11];
    const float* p_w   = (const float*)d_in[12];
    const float* p_b   = (const float*)d_in[13];
    const float* t_w   = (const float*)d_in[14];
    const float* t_b   = (const float*)d_in[15];

    const int N = in_sizes[0] / HID;   // 50000
    const int E = in_sizes[1] / 2;     // 800000
    const int* src = edges;
    const int* dst = edges + E;
    const int NB = (N + 255) >> BIN_SHIFT;   // 196

    char* w = (char*)d_ws;
    auto carve = [&](size_t bytes) {
        char* p = w;
        w += (bytes + 255) & ~size_t(255);
        return (void*)p;
    };
    u16*   hs        = (u16*)  carve((size_t)N * HID * 2);
    u16*   hbuf      = (u16*)  carve((size_t)N * HID * 2);
    u16*   xb        = (u16*)  carve((size_t)N * HID * 2);   // x in bf16
    u16*   wt1       = (u16*)  carve((size_t)HID * HID * 2); // W1^T bf16
    u16*   wt2       = (u16*)  carve((size_t)HID * HID * 2); // W2^T bf16
    float* dinv      = (float*)carve((size_t)N * 4);
    int*   row_start = (int*)  carve((size_t)(N + 1) * 4);
    int*   csr_src   = (int*)  carve((size_t)E * 4);
    uint2* staging   = (uint2*)carve((size_t)E * 8);
    int*   bincnt    = (int*)  carve(256 * 4);
    int*   bin_start = (int*)  carve(257 * 4);
    int*   bin_cursor= (int*)  carve(256 * 4);
    float* partials  = (float*)carve((size_t)CS_BLOCKS * HID * 4);
    float* colsum    = (float*)carve((size_t)HID * 4);

    // converts (independent of CSR chain)
    convert_wt<<<36, 256, 0, stream>>>(W1, wt1);
    convert_wt<<<36, 256, 0, stream>>>(W2, wt2);
    int n4 = N * HID / 4;
    convert_bf16<<<(n4 + 255) / 256, 256, 0, stream>>>((const float4*)x, (uint2*)xb, n4);

    // CSR build (bin-partitioned counting sort) + row_start + dinv
    hipMemsetAsync(bincnt, 0, 256 * 4, stream);
    binhist_kernel<<<1024, 256, 0, stream>>>(dst, bincnt, E, NB);
    binscan_kernel<<<1, 256, 0, stream>>>(bincnt, bin_start, bin_cursor, NB, E);
    binappend_kernel<<<(E + AP_CHUNK - 1) / AP_CHUNK, 256, 0, stream>>>(
        src, dst, bin_cursor, staging, E);
    binplace_kernel<<<NB, 256, 0, stream>>>(staging, bin_start, row_start,
                                            dinv, csr_src, N, E, NB);

    int gemm_blocks = (N + 63) / 64;
    int gthreads = N * 12;

    // layer 1
    gemm_mfma<<<gemm_blocks, 256, 0, stream>>>(xb, wt1, dinv, hs, N);
    gather_kernel<<<(gthreads + 255) / 256, 256, 0, stream>>>(
        (const uint4*)hs, row_start, csr_src, dinv, b1, (uint4*)hbuf, N);
    // layer 2
    gemm_mfma<<<gemm_blocks, 256, 0, stream>>>(hbuf, wt2, dinv, hs, N);
    gather_kernel<<<(gthreads + 255) / 256, 256, 0, stream>>>(
        (const uint4*)hs, row_start, csr_src, dinv, b2, (uint4*)hbuf, N);

    // pool + heads
    colsum_kernel<<<CS_BLOCKS, 256, 0, stream>>>((const uint4*)hbuf, partials, N);
    reduce_partials<<<24, 256, 0, stream>>>((const float4*)partials, (float4*)colsum, CS_BLOCKS);
    head_kernel<<<1, 128, 0, stream>>>(colsum, N, lin_w, lin_b,
        q_w, q_b, g_w, g_b, p_w, p_b, t_w, t_b, (float*)d_out);
}

// Round 7
// 154.493 us; speedup vs baseline: 3.2159x; 1.0279x over previous
//
#include <hip/hip_runtime.h>

#define HID 96
#define CS_BLOCKS 768   // colsum grid (3 per CU)
#define BIN_SHIFT 8     // 256 nodes per bin
#define AP_PER_T 16     // edges per thread in binappend
#define AP_CHUNK (256 * AP_PER_T)   // 4096 edges per WG

typedef unsigned int u32;
typedef unsigned short u16;
typedef __attribute__((ext_vector_type(8))) short bf16x8;
typedef __attribute__((ext_vector_type(4))) float f32x4;

// ---- bf16 helpers (storage-only bf16; all math in f32) ----
__device__ __forceinline__ float bl(u32 u) { return __uint_as_float(u << 16); }          // low bf16
__device__ __forceinline__ float bh(u32 u) { return __uint_as_float(u & 0xFFFF0000u); }  // high bf16
__device__ __forceinline__ u16 f2bf(float f) {  // round-to-nearest-even
    u32 u = __float_as_uint(f);
    return (u16)((u + 0x7FFFu + ((u >> 16) & 1u)) >> 16);
}
__device__ __forceinline__ u32 packbf(float a, float b) {
    return (u32)f2bf(a) | ((u32)f2bf(b) << 16);
}

// ---------------- tiny utility ----------------
__global__ void zero256(int* __restrict__ p) { p[threadIdx.x] = 0; }

// ---------------- CSR build, bin-partitioned ----------------

__global__ __launch_bounds__(256) void binhist_kernel(const int* __restrict__ dst,
        int* __restrict__ bincnt, int E, int nb) {
    __shared__ int h[256];
    int t = threadIdx.x;
    h[t] = 0;
    __syncthreads();
    for (int e = blockIdx.x * 256 + t; e < E; e += gridDim.x * 256)
        atomicAdd(&h[dst[e] >> BIN_SHIFT], 1);
    __syncthreads();
    if (t < nb && h[t]) atomicAdd(&bincnt[t], h[t]);
}

__global__ __launch_bounds__(256) void binscan_kernel(const int* __restrict__ bincnt,
        int* __restrict__ bin_start, int* __restrict__ bin_cursor, int nb, int E) {
    __shared__ int sh[256];
    int t = threadIdx.x;
    sh[t] = (t < nb) ? bincnt[t] : 0;
    __syncthreads();
    for (int off = 1; off < 256; off <<= 1) {
        int v = (t >= off) ? sh[t - off] : 0;
        __syncthreads();
        sh[t] += v;
        __syncthreads();
    }
    if (t < nb) {
        int s = (t == 0) ? 0 : sh[t - 1];
        bin_start[t] = s;
        bin_cursor[t] = s;
    }
    if (t == 0) bin_start[nb] = E;
}

// staging entry: src (24 bits) | local-dst (8 bits) << 24
__global__ __launch_bounds__(256) void binappend_kernel(const int* __restrict__ src,
        const int* __restrict__ dst, int* __restrict__ bin_cursor,
        u32* __restrict__ staging, int E) {
    __shared__ int cnt[256];
    __shared__ int pos[256];
    int t = threadIdx.x;
    cnt[t] = 0;
    __syncthreads();
    int base = blockIdx.x * AP_CHUNK + t;
    u32 pw[AP_PER_T];
    int bn[AP_PER_T];
#pragma unroll
    for (int j = 0; j < AP_PER_T; ++j) {
        int e = base + j * 256;
        if (e < E) {
            int s = src[e], d = dst[e];
            pw[j] = (u32)s | ((u32)(d & 255) << 24);
            bn[j] = d >> BIN_SHIFT;
            atomicAdd(&cnt[bn[j]], 1);
        } else bn[j] = -1;
    }
    __syncthreads();
    if (cnt[t]) pos[t] = atomicAdd(&bin_cursor[t], cnt[t]);
    __syncthreads();
#pragma unroll
    for (int j = 0; j < AP_PER_T; ++j) {
        if (bn[j] >= 0) {
            int p = atomicAdd(&pos[bn[j]], 1);
            staging[p] = pw[j];
        }
    }
}

__global__ __launch_bounds__(256) void binplace_kernel(const u32* __restrict__ staging,
        const int* __restrict__ bin_start, int* __restrict__ row_start,
        float* __restrict__ dinv, int* __restrict__ csr_src, int n, int E, int nb) {
    __shared__ int ncnt[256];
    __shared__ int sh[256];
    __shared__ int nstart[256];
    int b = blockIdx.x;
    int t = threadIdx.x;
    int nbase = b << BIN_SHIFT;
    int nnodes = min(256, n - nbase);
    int s0 = bin_start[b], s1 = bin_start[b + 1];
    ncnt[t] = 0;
    __syncthreads();
    for (int e = s0 + t; e < s1; e += 256)
        atomicAdd(&ncnt[staging[e] >> 24], 1);
    __syncthreads();
    int v0 = ncnt[t];
    sh[t] = v0;
    __syncthreads();
    for (int off = 1; off < 256; off <<= 1) {
        int v = (t >= off) ? sh[t - off] : 0;
        __syncthreads();
        sh[t] += v;
        __syncthreads();
    }
    int mystart = s0 + sh[t] - v0;   // exclusive prefix
    if (t < nnodes) {
        row_start[nbase + t] = mystart;
        dinv[nbase + t] = 1.0f / sqrtf((float)(v0 + 1));  // +1 self-loop
        nstart[t] = mystart;
    }
    if (b == nb - 1 && t == 0) row_start[n] = E;
    __syncthreads();
    for (int e = s0 + t; e < s1; e += 256) {
        u32 pr = staging[e];
        int slot = atomicAdd(&nstart[pr >> 24], 1);
        csr_src[slot] = (int)(pr & 0xFFFFFFu);
    }
}

// ---------------- converts ----------------
// W[k*96+col] f32 -> wt[col*96+k] bf16 (transpose)
__global__ __launch_bounds__(256) void convert_wt(const float* __restrict__ W,
        u16* __restrict__ wt) {
    int idx = blockIdx.x * 256 + threadIdx.x;
    if (idx < 96 * 96) {
        int col = idx / 96, k = idx - col * 96;
        wt[idx] = f2bf(W[k * 96 + col]);
    }
}

// ---------------- MFMA GEMM: hs[i,:] = bf16(dinv[i] * (in[i,:] @ W)) ----------------
// A-fragment loaders: 8 consecutive elements at a 32B-aligned offset
__device__ __forceinline__ bf16x8 load_a8(const u16* p) { return *(const bf16x8*)p; }
__device__ __forceinline__ bf16x8 load_a8(const float* p) {
    float4 v0 = *(const float4*)p;
    float4 v1 = *(const float4*)(p + 4);
    bf16x8 r;
    r[0] = (short)f2bf(v0.x); r[1] = (short)f2bf(v0.y);
    r[2] = (short)f2bf(v0.z); r[3] = (short)f2bf(v0.w);
    r[4] = (short)f2bf(v1.x); r[5] = (short)f2bf(v1.y);
    r[6] = (short)f2bf(v1.z); r[7] = (short)f2bf(v1.w);
    return r;
}

// in: [n x 96] row-major (f32 or bf16); wt: [96 x 96] bf16 transposed (wt[col*96+k]).
// 4 waves/block, 16 rows/wave, 64 rows/block. 18 MFMA (6 N-tiles x 3 K-steps) per wave.
template <typename TI>
__global__ __launch_bounds__(256) void gemm_mfma(const TI* __restrict__ xb,
        const u16* __restrict__ wt, const float* __restrict__ dinv,
        u16* __restrict__ out, int n) {
    __shared__ uint4 Wt4[96 * 13];   // 96 rows x 104 bf16 (208 B = 13 uint4), padded
    int t = threadIdx.x;
    const uint4* wsrc = (const uint4*)wt;
    for (int idx = t; idx < 96 * 12; idx += 256) {
        int row = idx / 12, c = idx - row * 12;
        Wt4[row * 13 + c] = wsrc[idx];
    }
    __syncthreads();

    int wave = t >> 6, lane = t & 63;
    int row0 = blockIdx.x * 64 + wave * 16;
    int kb = lane >> 4;              // 0..3 (k-block)
    int rc = lane & 15;              // row (A) / col (B,C) within tile
    int arow = row0 + rc;
    int ar = (arow < n) ? arow : 0;  // clamp OOB loads (stores guarded below)

    // A fragments: lane reads 8 consecutive elements at k = kk*32 + kb*8
    const TI* ap = xb + (size_t)ar * 96 + kb * 8;
    bf16x8 a0 = load_a8(ap);
    bf16x8 a1 = load_a8(ap + 32);
    bf16x8 a2 = load_a8(ap + 64);

    const u16* wbase = (const u16*)Wt4;
    f32x4 acc[6];
#pragma unroll
    for (int j = 0; j < 6; ++j) acc[j] = (f32x4){0.f, 0.f, 0.f, 0.f};

#pragma unroll
    for (int j = 0; j < 6; ++j) {
        int col = j * 16 + rc;
        const u16* wp = wbase + col * 104 + kb * 8;
        bf16x8 b0 = *(const bf16x8*)(wp);
        bf16x8 b1 = *(const bf16x8*)(wp + 32);
        bf16x8 b2 = *(const bf16x8*)(wp + 64);
        acc[j] = __builtin_amdgcn_mfma_f32_16x16x32_bf16(a0, b0, acc[j], 0, 0, 0);
        acc[j] = __builtin_amdgcn_mfma_f32_16x16x32_bf16(a1, b1, acc[j], 0, 0, 0);
        acc[j] = __builtin_amdgcn_mfma_f32_16x16x32_bf16(a2, b2, acc[j], 0, 0, 0);
    }

    // C/D layout: col = rc, row = kb*4 + r  [m89-verified]
#pragma unroll
    for (int r = 0; r < 4; ++r) {
        int row = row0 + kb * 4 + r;
        if (row < n) {
            float dv = dinv[row];
            u16* orow = out + (size_t)row * 96 + rc;
#pragma unroll
            for (int j = 0; j < 6; ++j)
                orow[j * 16] = f2bf(dv * acc[j][r]);
        }
    }
}

// ---------------- gather aggregation + scale + bias + relu (bf16 rows) ----------------
__global__ void gather_kernel(const uint4* __restrict__ hs, const int* __restrict__ row_start,
        const int* __restrict__ csr_src, const float* __restrict__ dinv,
        const float* __restrict__ bias, uint4* __restrict__ out, int n) {
    int gid = blockIdx.x * blockDim.x + threadIdx.x;
    if (gid >= n * 12) return;
    int i = gid / 12, q = gid - i * 12;
    uint4 v = hs[i * 12 + q];   // self-loop term (pre-scaled by dinv[i])
    float acc[8] = { bl(v.x), bh(v.x), bl(v.y), bh(v.y),
                     bl(v.z), bh(v.z), bl(v.w), bh(v.w) };
    int e = row_start[i], e1 = row_start[i + 1];
    for (; e + 1 < e1; e += 2) {
        int s0 = csr_src[e], s1 = csr_src[e + 1];
        uint4 a = hs[s0 * 12 + q];
        uint4 b = hs[s1 * 12 + q];
        acc[0] += bl(a.x); acc[1] += bh(a.x); acc[2] += bl(a.y); acc[3] += bh(a.y);
        acc[4] += bl(a.z); acc[5] += bh(a.z); acc[6] += bl(a.w); acc[7] += bh(a.w);
        acc[0] += bl(b.x); acc[1] += bh(b.x); acc[2] += bl(b.y); acc[3] += bh(b.y);
        acc[4] += bl(b.z); acc[5] += bh(b.z); acc[6] += bl(b.w); acc[7] += bh(b.w);
    }
    if (e < e1) {
        int s0 = csr_src[e];
        uint4 a = hs[s0 * 12 + q];
        acc[0] += bl(a.x); acc[1] += bh(a.x); acc[2] += bl(a.y); acc[3] += bh(a.y);
        acc[4] += bl(a.z); acc[5] += bh(a.z); acc[6] += bl(a.w); acc[7] += bh(a.w);
    }
    float dv = dinv[i];
    const float4 b0 = reinterpret_cast<const float4*>(bias)[q * 2];
    const float4 b1 = reinterpret_cast<const float4*>(bias)[q * 2 + 1];
    float r0 = fmaxf(fmaf(acc[0], dv, b0.x), 0.f);
    float r1 = fmaxf(fmaf(acc[1], dv, b0.y), 0.f);
    float r2 = fmaxf(fmaf(acc[2], dv, b0.z), 0.f);
    float r3 = fmaxf(fmaf(acc[3], dv, b0.w), 0.f);
    float r4 = fmaxf(fmaf(acc[4], dv, b1.x), 0.f);
    float r5 = fmaxf(fmaf(acc[5], dv, b1.y), 0.f);
    float r6 = fmaxf(fmaf(acc[6], dv, b1.z), 0.f);
    float r7 = fmaxf(fmaf(acc[7], dv, b1.w), 0.f);
    uint4 o;
    o.x = packbf(r0, r1); o.y = packbf(r2, r3);
    o.z = packbf(r4, r5); o.w = packbf(r6, r7);
    out[i * 12 + q] = o;
}

// ---------------- column-sum of bf16 h2 [n x 96]: stage 1 ----------------
__global__ __launch_bounds__(256) void colsum_kernel(const uint4* __restrict__ h2,
        float* __restrict__ partials, int n) {
    int t = threadIdx.x;
    int q = t % 12, g = t / 12;  // g in 0..20 used (252 threads)
    float acc[8] = {0.f, 0.f, 0.f, 0.f, 0.f, 0.f, 0.f, 0.f};
    if (g < 21) {
        for (int r = blockIdx.x * 21 + g; r < n; r += CS_BLOCKS * 21) {
            uint4 v = h2[r * 12 + q];
            acc[0] += bl(v.x); acc[1] += bh(v.x); acc[2] += bl(v.y); acc[3] += bh(v.y);
            acc[4] += bl(v.z); acc[5] += bh(v.z); acc[6] += bl(v.w); acc[7] += bh(v.w);
        }
    }
    __shared__ float sh[21][96];
    if (g < 21) {
#pragma unroll
        for (int j = 0; j < 8; ++j) sh[g][q * 8 + j] = acc[j];
    }
    __syncthreads();
    if (t < 96) {
        float s = 0.f;
#pragma unroll
        for (int gg = 0; gg < 21; ++gg) s += sh[gg][t];
        partials[blockIdx.x * 96 + t] = s;
    }
}

// ---------------- column-sum stage 2 ----------------
__global__ __launch_bounds__(256) void reduce_partials(const float4* __restrict__ partials,
        float4* __restrict__ colsum, int nb) {
    int q = blockIdx.x;
    int t = threadIdx.x;
    float4 acc = {0.f, 0.f, 0.f, 0.f};
    for (int b = t; b < nb; b += 256) {
        float4 v = partials[b * 24 + q];
        acc.x += v.x; acc.y += v.y; acc.z += v.z; acc.w += v.w;
    }
    __shared__ float4 sh[256];
    sh[t] = acc;
    __syncthreads();
    for (int off = 128; off > 0; off >>= 1) {
        if (t < off) {
            sh[t].x += sh[t + off].x; sh[t].y += sh[t + off].y;
            sh[t].z += sh[t + off].z; sh[t].w += sh[t + off].w;
        }
        __syncthreads();
    }
    if (t == 0) colsum[q] = sh[0];
}

// ---------------- final MLP heads (single block) ----------------
__global__ __launch_bounds__(128) void head_kernel(const float* __restrict__ colsum, int n,
        const float* __restrict__ lin_w, const float* __restrict__ lin_b,
        const float* __restrict__ q_w, const float* __restrict__ q_b,
        const float* __restrict__ g_w, const float* __restrict__ g_b,
        const float* __restrict__ p_w, const float* __restrict__ p_b,
        const float* __restrict__ t_w, const float* __restrict__ t_b,
        float* __restrict__ out) {
    __shared__ float hm[96];
    __shared__ float h[96];
    int t = threadIdx.x;
    if (t < 96) hm[t] = colsum[t] / (float)n;
    __syncthreads();
    if (t < 96) {
        float s = lin_b[t];
        for (int k = 0; k < 96; ++k) s = fmaf(hm[k], lin_w[k * 96 + t], s);
        h[t] = fmaxf(s, 0.f);
    }
    __syncthreads();
    if (t < 43) {
        float s;
        if (t < 16) {
            s = q_b[t];
            for (int k = 0; k < 96; ++k) s = fmaf(h[k], q_w[k * 16 + t], s);
        } else if (t < 24) {
            int j = t - 16;
            s = g_b[j];
            for (int k = 0; k < 96; ++k) s = fmaf(h[k], g_w[k * 8 + j], s);
        } else if (t < 28) {
            int j = t - 24;
            s = p_b[j];
            for (int k = 0; k < 96; ++k) s = fmaf(h[k], p_w[k * 4 + j], s);
        } else {
            int j = t - 28;
            s = t_b[j];
            for (int k = 0; k < 96; ++k) s = fmaf(h[k], t_w[k * 15 + j], s);
        }
        out[t] = s;
    }
}

extern "C" void kernel_launch(void* const* d_in, const int* in_sizes, int n_in,
                              void* d_out, int out_size, void* d_ws, size_t ws_size,
                              hipStream_t stream) {
    const float* x     = (const float*)d_in[0];
    const int*   edges = (const int*)d_in[1];
    const float* W1    = (const float*)d_in[2];
    const float* b1    = (const float*)d_in[3];
    const float* W2    = (const float*)d_in[4];
    const float* b2    = (const float*)d_in[5];
    const float* lin_w = (const float*)d_in[6];
    const float* lin_b = (const float*)d_in[7];
    const float* q_w   = (const float*)d_in[8];
    const float* q_b   = (const float*)d_in[9];
    const float* g_w   = (const float*)d_in[10];
    const float* g_b   = (const float*)d_in[11];
    const float* p_w   = (const float*)d_in[12];
    const float* p_b   = (const float*)d_in[13];
    const float* t_w   = (const float*)d_in[14];
    const float* t_b   = (const float*)d_in[15];

    const int N = in_sizes[0] / HID;   // 50000
    const int E = in_sizes[1] / 2;     // 800000
    const int* src = edges;
    const int* dst = edges + E;
    const int NB = (N + 255) >> BIN_SHIFT;   // 196

    char* w = (char*)d_ws;
    auto carve = [&](size_t bytes) {
        char* p = w;
        w += (bytes + 255) & ~size_t(255);
        return (void*)p;
    };
    u16*   hs        = (u16*)  carve((size_t)N * HID * 2);
    u16*   hbuf      = (u16*)  carve((size_t)N * HID * 2);
    u16*   wt1       = (u16*)  carve((size_t)HID * HID * 2); // W1^T bf16
    u16*   wt2       = (u16*)  carve((size_t)HID * HID * 2); // W2^T bf16
    float* dinv      = (float*)carve((size_t)N * 4);
    int*   row_start = (int*)  carve((size_t)(N + 1) * 4);
    int*   csr_src   = (int*)  carve((size_t)E * 4);
    u32*   staging   = (u32*)  carve((size_t)E * 4);
    int*   bincnt    = (int*)  carve(256 * 4);
    int*   bin_start = (int*)  carve(257 * 4);
    int*   bin_cursor= (int*)  carve(256 * 4);
    float* partials  = (float*)carve((size_t)CS_BLOCKS * HID * 4);
    float* colsum    = (float*)carve((size_t)HID * 4);

    // CSR build (bin-partitioned counting sort) + row_start + dinv
    zero256<<<1, 256, 0, stream>>>(bincnt);
    convert_wt<<<36, 256, 0, stream>>>(W1, wt1);
    convert_wt<<<36, 256, 0, stream>>>(W2, wt2);
    binhist_kernel<<<1024, 256, 0, stream>>>(dst, bincnt, E, NB);
    binscan_kernel<<<1, 256, 0, stream>>>(bincnt, bin_start, bin_cursor, NB, E);
    binappend_kernel<<<(E + AP_CHUNK - 1) / AP_CHUNK, 256, 0, stream>>>(
        src, dst, bin_cursor, staging, E);
    binplace_kernel<<<NB, 256, 0, stream>>>(staging, bin_start, row_start,
                                            dinv, csr_src, N, E, NB);

    int gemm_blocks = (N + 63) / 64;
    int gthreads = N * 12;

    // layer 1 (A loaded as f32, packed to bf16 in-register)
    gemm_mfma<float><<<gemm_blocks, 256, 0, stream>>>(x, wt1, dinv, hs, N);
    gather_kernel<<<(gthreads + 255) / 256, 256, 0, stream>>>(
        (const uint4*)hs, row_start, csr_src, dinv, b1, (uint4*)hbuf, N);
    // layer 2
    gemm_mfma<u16><<<gemm_blocks, 256, 0, stream>>>(hbuf, wt2, dinv, hs, N);
    gather_kernel<<<(gthreads + 255) / 256, 256, 0, stream>>>(
        (const uint4*)hs, row_start, csr_src, dinv, b2, (uint4*)hbuf, N);

    // pool + heads
    colsum_kernel<<<CS_BLOCKS, 256, 0, stream>>>((const uint4*)hbuf, partials, N);
    reduce_partials<<<24, 256, 0, stream>>>((const float4*)partials, (float4*)colsum, CS_BLOCKS);
    head_kernel<<<1, 128, 0, stream>>>(colsum, N, lin_w, lin_b,
        q_w, q_b, g_w, g_b, p_w, p_b, t_w, t_b, (float*)d_out);
}

// Round 8
// 137.436 us; speedup vs baseline: 3.6150x; 1.1241x over previous
//
#include <hip/hip_runtime.h>

#define HID 96
#define BIN_SHIFT 8     // 256 nodes per bin
#define AP_PER_T 16     // edges per thread in binappend
#define AP_CHUNK (256 * AP_PER_T)   // 4096 edges per WG
#define HIST_BLOCKS 64

typedef unsigned int u32;
typedef unsigned short u16;
typedef __attribute__((ext_vector_type(8))) short bf16x8;
typedef __attribute__((ext_vector_type(4))) float f32x4;

// ---- bf16 helpers (storage-only bf16; all math in f32) ----
__device__ __forceinline__ float bl(u32 u) { return __uint_as_float(u << 16); }
__device__ __forceinline__ float bh(u32 u) { return __uint_as_float(u & 0xFFFF0000u); }
__device__ __forceinline__ u16 f2bf(float f) {  // round-to-nearest-even
    u32 u = __float_as_uint(f);
    return (u16)((u + 0x7FFFu + ((u >> 16) & 1u)) >> 16);
}
__device__ __forceinline__ u32 packbf(float a, float b) {
    return (u32)f2bf(a) | ((u32)f2bf(b) << 16);
}

// ---------------- MFMA GEMM body (shared by mega1 role and gemm2) ----------------
// A-fragment loaders: 8 consecutive elements at a 16B-aligned offset
__device__ __forceinline__ bf16x8 load_a8(const u16* p) { return *(const bf16x8*)p; }
__device__ __forceinline__ bf16x8 load_a8(const float* p) {
    float4 v0 = *(const float4*)p;
    float4 v1 = *(const float4*)(p + 4);
    bf16x8 r;
    r[0] = (short)f2bf(v0.x); r[1] = (short)f2bf(v0.y);
    r[2] = (short)f2bf(v0.z); r[3] = (short)f2bf(v0.w);
    r[4] = (short)f2bf(v1.x); r[5] = (short)f2bf(v1.y);
    r[6] = (short)f2bf(v1.z); r[7] = (short)f2bf(v1.w);
    return r;
}

// out[i,:] = bf16( (SCALE ? dinv[i] : 1) * (in[i,:] @ W) )
// W: [96 x 96] f32 row-major (W[k*96+col]); staged to LDS bf16 transposed in-kernel.
// 4 waves/block, 16 rows/wave, 64 rows/block. 18 MFMA per wave.
template <typename TI, bool SCALE>
__device__ __forceinline__ void gemm_body(int bid, int t, const TI* __restrict__ xb,
        const float* __restrict__ W, const float* __restrict__ dinv,
        u16* __restrict__ out, int n, uint4* Wt4) {
    // stage W (f32) -> bf16 transposed: Wt4[col*13 + c] = bf16 of W[k=c*8..c*8+7][col]
    for (int idx = t; idx < 96 * 12; idx += 256) {
        int col = idx % 96, c = idx / 96;
        const float* wp = W + c * 8 * 96 + col;
        uint4 pk;
        pk.x = packbf(wp[0],   wp[96]);
        pk.y = packbf(wp[192], wp[288]);
        pk.z = packbf(wp[384], wp[480]);
        pk.w = packbf(wp[576], wp[672]);
        Wt4[col * 13 + c] = pk;
    }
    __syncthreads();

    int wave = t >> 6, lane = t & 63;
    int row0 = bid * 64 + wave * 16;
    int kb = lane >> 4;              // 0..3 (k-block)
    int rc = lane & 15;              // row (A) / col (B,C) within tile
    int arow = row0 + rc;
    int ar = (arow < n) ? arow : 0;  // clamp OOB loads (stores guarded below)

    const TI* ap = xb + (size_t)ar * 96 + kb * 8;
    bf16x8 a0 = load_a8(ap);
    bf16x8 a1 = load_a8(ap + 32);
    bf16x8 a2 = load_a8(ap + 64);

    const u16* wbase = (const u16*)Wt4;
    f32x4 acc[6];
#pragma unroll
    for (int j = 0; j < 6; ++j) acc[j] = (f32x4){0.f, 0.f, 0.f, 0.f};

#pragma unroll
    for (int j = 0; j < 6; ++j) {
        int col = j * 16 + rc;
        const u16* wp = wbase + col * 104 + kb * 8;
        bf16x8 b0 = *(const bf16x8*)(wp);
        bf16x8 b1 = *(const bf16x8*)(wp + 32);
        bf16x8 b2 = *(const bf16x8*)(wp + 64);
        acc[j] = __builtin_amdgcn_mfma_f32_16x16x32_bf16(a0, b0, acc[j], 0, 0, 0);
        acc[j] = __builtin_amdgcn_mfma_f32_16x16x32_bf16(a1, b1, acc[j], 0, 0, 0);
        acc[j] = __builtin_amdgcn_mfma_f32_16x16x32_bf16(a2, b2, acc[j], 0, 0, 0);
    }

    // C/D layout: col = rc, row = kb*4 + r  [m89-verified]
#pragma unroll
    for (int r = 0; r < 4; ++r) {
        int row = row0 + kb * 4 + r;
        if (row < n) {
            float dv = SCALE ? dinv[row] : 1.0f;
            u16* orow = out + (size_t)row * 96 + rc;
#pragma unroll
            for (int j = 0; j < 6; ++j)
                orow[j * 16] = f2bf(dv * acc[j][r]);
        }
    }
}

// ---------------- K1: fused bin-histogram (64 blocks) + layer-1 GEMM ----------------
__global__ __launch_bounds__(256) void mega1_kernel(const int* __restrict__ dst,
        int* __restrict__ hist64, const float* __restrict__ x,
        const float* __restrict__ W1, u16* __restrict__ hs_raw, int n, int E) {
    __shared__ uint4 smem[96 * 13];   // 19968 B (hist role reuses first 1 KB)
    int b = blockIdx.x;
    int t = threadIdx.x;
    if (b < HIST_BLOCKS) {
        int* h = (int*)smem;
        h[t] = 0;
        __syncthreads();
        for (int e = b * 256 + t; e < E; e += HIST_BLOCKS * 256)
            atomicAdd(&h[dst[e] >> BIN_SHIFT], 1);
        __syncthreads();
        hist64[b * 256 + t] = h[t];   // private per-block histogram, no global atomics
    } else {
        gemm_body<float, false>(b - HIST_BLOCKS, t, x, W1, nullptr, hs_raw, n, smem);
    }
}

// ---------------- K2: scan of 64 private histograms -> bin_start/cursor ----------------
__global__ __launch_bounds__(256) void binscan_kernel(const int* __restrict__ hist64,
        int* __restrict__ bin_start, int* __restrict__ bin_cursor, int nb, int E) {
    __shared__ int sh[256];
    int t = threadIdx.x;
    int s = 0;
#pragma unroll 8
    for (int b = 0; b < HIST_BLOCKS; ++b) s += hist64[b * 256 + t];
    sh[t] = s;
    __syncthreads();
    for (int off = 1; off < 256; off <<= 1) {
        int v = (t >= off) ? sh[t - off] : 0;
        __syncthreads();
        sh[t] += v;
        __syncthreads();
    }
    if (t < nb) {
        int st = (t == 0) ? 0 : sh[t - 1];
        bin_start[t] = st;
        bin_cursor[t] = st;
    }
    if (t == 0) bin_start[nb] = E;
}

// ---------------- K3: partition edges into bin-grouped staging ----------------
// staging entry: src (24 bits) | local-dst (8 bits) << 24
__global__ __launch_bounds__(256) void binappend_kernel(const int* __restrict__ src,
        const int* __restrict__ dst, int* __restrict__ bin_cursor,
        u32* __restrict__ staging, int E) {
    __shared__ int cnt[256];
    __shared__ int pos[256];
    int t = threadIdx.x;
    cnt[t] = 0;
    __syncthreads();
    int base = blockIdx.x * AP_CHUNK + t;
    u32 pw[AP_PER_T];
    int bn[AP_PER_T];
#pragma unroll
    for (int j = 0; j < AP_PER_T; ++j) {
        int e = base + j * 256;
        if (e < E) {
            int s = src[e], d = dst[e];
            pw[j] = (u32)s | ((u32)(d & 255) << 24);
            bn[j] = d >> BIN_SHIFT;
            atomicAdd(&cnt[bn[j]], 1);
        } else bn[j] = -1;
    }
    __syncthreads();
    if (cnt[t]) pos[t] = atomicAdd(&bin_cursor[t], cnt[t]);
    __syncthreads();
#pragma unroll
    for (int j = 0; j < AP_PER_T; ++j) {
        if (bn[j] >= 0) {
            int p = atomicAdd(&pos[bn[j]], 1);
            staging[p] = pw[j];
        }
    }
}

// ---------------- K4: per-bin node hist/scan -> row_start, dinv; place csr_src ----------------
__global__ __launch_bounds__(256) void binplace_kernel(const u32* __restrict__ staging,
        const int* __restrict__ bin_start, int* __restrict__ row_start,
        float* __restrict__ dinv, int* __restrict__ csr_src, int n, int E, int nb) {
    __shared__ int ncnt[256];
    __shared__ int sh[256];
    __shared__ int nstart[256];
    int b = blockIdx.x;
    int t = threadIdx.x;
    int nbase = b << BIN_SHIFT;
    int nnodes = min(256, n - nbase);
    int s0 = bin_start[b], s1 = bin_start[b + 1];
    ncnt[t] = 0;
    __syncthreads();
    for (int e = s0 + t; e < s1; e += 256)
        atomicAdd(&ncnt[staging[e] >> 24], 1);
    __syncthreads();
    int v0 = ncnt[t];
    sh[t] = v0;
    __syncthreads();
    for (int off = 1; off < 256; off <<= 1) {
        int v = (t >= off) ? sh[t - off] : 0;
        __syncthreads();
        sh[t] += v;
        __syncthreads();
    }
    int mystart = s0 + sh[t] - v0;   // exclusive prefix
    if (t < nnodes) {
        row_start[nbase + t] = mystart;
        dinv[nbase + t] = 1.0f / sqrtf((float)(v0 + 1));  // +1 self-loop
        nstart[t] = mystart;
    }
    if (b == nb - 1 && t == 0) row_start[n] = E;
    __syncthreads();
    for (int e = s0 + t; e < s1; e += 256) {
        u32 pr = staging[e];
        int slot = atomicAdd(&nstart[pr >> 24], 1);
        csr_src[slot] = (int)(pr & 0xFFFFFFu);
    }
}

// ---------------- K5: gather1 — hs_raw unscaled, apply dinv[s] per row ----------------
// out[i,:] = relu(dinv[i]*(dinv[i]*hsr[i,:] + sum_e dinv[s]*hsr[s,:]) + b)
__global__ void gather1_kernel(const uint4* __restrict__ hs, const int* __restrict__ row_start,
        const int* __restrict__ csr_src, const float* __restrict__ dinv,
        const float* __restrict__ bias, uint4* __restrict__ out, int n) {
    int gid = blockIdx.x * blockDim.x + threadIdx.x;
    if (gid >= n * 12) return;
    int i = gid / 12, q = gid - i * 12;
    float dvi = dinv[i];
    uint4 v = hs[i * 12 + q];   // self-loop term (unscaled)
    float acc[8] = { dvi * bl(v.x), dvi * bh(v.x), dvi * bl(v.y), dvi * bh(v.y),
                     dvi * bl(v.z), dvi * bh(v.z), dvi * bl(v.w), dvi * bh(v.w) };
    int e = row_start[i], e1 = row_start[i + 1];
    for (; e + 1 < e1; e += 2) {
        int s0 = csr_src[e], s1 = csr_src[e + 1];
        float dv0 = dinv[s0], dv1 = dinv[s1];
        uint4 a = hs[s0 * 12 + q];
        uint4 b = hs[s1 * 12 + q];
        acc[0] = fmaf(bl(a.x), dv0, acc[0]); acc[1] = fmaf(bh(a.x), dv0, acc[1]);
        acc[2] = fmaf(bl(a.y), dv0, acc[2]); acc[3] = fmaf(bh(a.y), dv0, acc[3]);
        acc[4] = fmaf(bl(a.z), dv0, acc[4]); acc[5] = fmaf(bh(a.z), dv0, acc[5]);
        acc[6] = fmaf(bl(a.w), dv0, acc[6]); acc[7] = fmaf(bh(a.w), dv0, acc[7]);
        acc[0] = fmaf(bl(b.x), dv1, acc[0]); acc[1] = fmaf(bh(b.x), dv1, acc[1]);
        acc[2] = fmaf(bl(b.y), dv1, acc[2]); acc[3] = fmaf(bh(b.y), dv1, acc[3]);
        acc[4] = fmaf(bl(b.z), dv1, acc[4]); acc[5] = fmaf(bh(b.z), dv1, acc[5]);
        acc[6] = fmaf(bl(b.w), dv1, acc[6]); acc[7] = fmaf(bh(b.w), dv1, acc[7]);
    }
    if (e < e1) {
        int s0 = csr_src[e];
        float dv0 = dinv[s0];
        uint4 a = hs[s0 * 12 + q];
        acc[0] = fmaf(bl(a.x), dv0, acc[0]); acc[1] = fmaf(bh(a.x), dv0, acc[1]);
        acc[2] = fmaf(bl(a.y), dv0, acc[2]); acc[3] = fmaf(bh(a.y), dv0, acc[3]);
        acc[4] = fmaf(bl(a.z), dv0, acc[4]); acc[5] = fmaf(bh(a.z), dv0, acc[5]);
        acc[6] = fmaf(bl(a.w), dv0, acc[6]); acc[7] = fmaf(bh(a.w), dv0, acc[7]);
    }
    const float4 b0 = reinterpret_cast<const float4*>(bias)[q * 2];
    const float4 b1 = reinterpret_cast<const float4*>(bias)[q * 2 + 1];
    uint4 o;
    o.x = packbf(fmaxf(fmaf(acc[0], dvi, b0.x), 0.f), fmaxf(fmaf(acc[1], dvi, b0.y), 0.f));
    o.y = packbf(fmaxf(fmaf(acc[2], dvi, b0.z), 0.f), fmaxf(fmaf(acc[3], dvi, b0.w), 0.f));
    o.z = packbf(fmaxf(fmaf(acc[4], dvi, b1.x), 0.f), fmaxf(fmaf(acc[5], dvi, b1.y), 0.f));
    o.w = packbf(fmaxf(fmaf(acc[6], dvi, b1.z), 0.f), fmaxf(fmaf(acc[7], dvi, b1.w), 0.f));
    out[i * 12 + q] = o;
}

// ---------------- K6: gemm2 (hs pre-scaled by dinv) ----------------
__global__ __launch_bounds__(256) void gemm2_kernel(const u16* __restrict__ xb,
        const float* __restrict__ W, const float* __restrict__ dinv,
        u16* __restrict__ out, int n) {
    __shared__ uint4 smem[96 * 13];
    gemm_body<u16, true>(blockIdx.x, threadIdx.x, xb, W, dinv, out, n, smem);
}

// ---------------- K7: gather2 fused with mean-pool partials (h2 never stored) ----------------
__global__ __launch_bounds__(256) void gather2_pool_kernel(const uint4* __restrict__ hs,
        const int* __restrict__ row_start, const int* __restrict__ csr_src,
        const float* __restrict__ dinv, const float* __restrict__ bias,
        float* __restrict__ partials, int n) {
    __shared__ float sh[22][96];
    int t = threadIdx.x;
    for (int idx = t; idx < 22 * 96; idx += 256) (&sh[0][0])[idx] = 0.f;
    __syncthreads();

    int gid = blockIdx.x * blockDim.x + t;
    bool valid = gid < n * 12;
    float r[8] = {0.f, 0.f, 0.f, 0.f, 0.f, 0.f, 0.f, 0.f};
    int q = 0;
    if (valid) {
        int i = gid / 12; q = gid - i * 12;
        uint4 v = hs[i * 12 + q];   // self-loop (pre-scaled)
        float acc[8] = { bl(v.x), bh(v.x), bl(v.y), bh(v.y),
                         bl(v.z), bh(v.z), bl(v.w), bh(v.w) };
        int e = row_start[i], e1 = row_start[i + 1];
        for (; e + 1 < e1; e += 2) {
            int s0 = csr_src[e], s1 = csr_src[e + 1];
            uint4 a = hs[s0 * 12 + q];
            uint4 b = hs[s1 * 12 + q];
            acc[0] += bl(a.x); acc[1] += bh(a.x); acc[2] += bl(a.y); acc[3] += bh(a.y);
            acc[4] += bl(a.z); acc[5] += bh(a.z); acc[6] += bl(a.w); acc[7] += bh(a.w);
            acc[0] += bl(b.x); acc[1] += bh(b.x); acc[2] += bl(b.y); acc[3] += bh(b.y);
            acc[4] += bl(b.z); acc[5] += bh(b.z); acc[6] += bl(b.w); acc[7] += bh(b.w);
        }
        if (e < e1) {
            int s0 = csr_src[e];
            uint4 a = hs[s0 * 12 + q];
            acc[0] += bl(a.x); acc[1] += bh(a.x); acc[2] += bl(a.y); acc[3] += bh(a.y);
            acc[4] += bl(a.z); acc[5] += bh(a.z); acc[6] += bl(a.w); acc[7] += bh(a.w);
        }
        float dv = dinv[i];
        const float4 b0 = reinterpret_cast<const float4*>(bias)[q * 2];
        const float4 b1 = reinterpret_cast<const float4*>(bias)[q * 2 + 1];
        r[0] = fmaxf(fmaf(acc[0], dv, b0.x), 0.f);
        r[1] = fmaxf(fmaf(acc[1], dv, b0.y), 0.f);
        r[2] = fmaxf(fmaf(acc[2], dv, b0.z), 0.f);
        r[3] = fmaxf(fmaf(acc[3], dv, b0.w), 0.f);
        r[4] = fmaxf(fmaf(acc[4], dv, b1.x), 0.f);
        r[5] = fmaxf(fmaf(acc[5], dv, b1.y), 0.f);
        r[6] = fmaxf(fmaf(acc[6], dv, b1.z), 0.f);
        r[7] = fmaxf(fmaf(acc[7], dv, b1.w), 0.f);
    }
    // tree-reduce into per-block column partials: group g covers all 12 q's once
    int g = t / 12;
#pragma unroll
    for (int j = 0; j < 8; ++j) sh[g][q * 8 + j] += r[j];   // distinct columns per group
    __syncthreads();
    if (t < 96) {
        float s = 0.f;
#pragma unroll
        for (int gg = 0; gg < 22; ++gg) s += sh[gg][t];
        partials[blockIdx.x * 96 + t] = s;
    }
}

// ---------------- K8: reduce partials ----------------
__global__ __launch_bounds__(256) void reduce_partials(const float4* __restrict__ partials,
        float4* __restrict__ colsum, int nb) {
    int q = blockIdx.x;
    int t = threadIdx.x;
    float4 acc = {0.f, 0.f, 0.f, 0.f};
    for (int b = t; b < nb; b += 256) {
        float4 v = partials[b * 24 + q];
        acc.x += v.x; acc.y += v.y; acc.z += v.z; acc.w += v.w;
    }
    __shared__ float4 sh[256];
    sh[t] = acc;
    __syncthreads();
    for (int off = 128; off > 0; off >>= 1) {
        if (t < off) {
            sh[t].x += sh[t + off].x; sh[t].y += sh[t + off].y;
            sh[t].z += sh[t + off].z; sh[t].w += sh[t + off].w;
        }
        __syncthreads();
    }
    if (t == 0) colsum[q] = sh[0];
}

// ---------------- K9: final MLP heads ----------------
__global__ __launch_bounds__(128) void head_kernel(const float* __restrict__ colsum, int n,
        const float* __restrict__ lin_w, const float* __restrict__ lin_b,
        const float* __restrict__ q_w, const float* __restrict__ q_b,
        const float* __restrict__ g_w, const float* __restrict__ g_b,
        const float* __restrict__ p_w, const float* __restrict__ p_b,
        const float* __restrict__ t_w, const float* __restrict__ t_b,
        float* __restrict__ out) {
    __shared__ float hm[96];
    __shared__ float h[96];
    int t = threadIdx.x;
    if (t < 96) hm[t] = colsum[t] / (float)n;
    __syncthreads();
    if (t < 96) {
        float s = lin_b[t];
        for (int k = 0; k < 96; ++k) s = fmaf(hm[k], lin_w[k * 96 + t], s);
        h[t] = fmaxf(s, 0.f);
    }
    __syncthreads();
    if (t < 43) {
        float s;
        if (t < 16) {
            s = q_b[t];
            for (int k = 0; k < 96; ++k) s = fmaf(h[k], q_w[k * 16 + t], s);
        } else if (t < 24) {
            int j = t - 16;
            s = g_b[j];
            for (int k = 0; k < 96; ++k) s = fmaf(h[k], g_w[k * 8 + j], s);
        } else if (t < 28) {
            int j = t - 24;
            s = p_b[j];
            for (int k = 0; k < 96; ++k) s = fmaf(h[k], p_w[k * 4 + j], s);
        } else {
            int j = t - 28;
            s = t_b[j];
            for (int k = 0; k < 96; ++k) s = fmaf(h[k], t_w[k * 15 + j], s);
        }
        out[t] = s;
    }
}

extern "C" void kernel_launch(void* const* d_in, const int* in_sizes, int n_in,
                              void* d_out, int out_size, void* d_ws, size_t ws_size,
                              hipStream_t stream) {
    const float* x     = (const float*)d_in[0];
    const int*   edges = (const int*)d_in[1];
    const float* W1    = (const float*)d_in[2];
    const float* b1    = (const float*)d_in[3];
    const float* W2    = (const float*)d_in[4];
    const float* b2    = (const float*)d_in[5];
    const float* lin_w = (const float*)d_in[6];
    const float* lin_b = (const float*)d_in[7];
    const float* q_w   = (const float*)d_in[8];
    const float* q_b   = (const float*)d_in[9];
    const float* g_w   = (const float*)d_in[10];
    const float* g_b   = (const float*)d_in[11];
    const float* p_w   = (const float*)d_in[12];
    const float* p_b   = (const float*)d_in[13];
    const float* t_w   = (const float*)d_in[14];
    const float* t_b   = (const float*)d_in[15];

    const int N = in_sizes[0] / HID;   // 50000
    const int E = in_sizes[1] / 2;     // 800000
    const int* src = edges;
    const int* dst = edges + E;
    const int NB = (N + 255) >> BIN_SHIFT;   // 196

    char* w = (char*)d_ws;
    auto carve = [&](size_t bytes) {
        char* p = w;
        w += (bytes + 255) & ~size_t(255);
        return (void*)p;
    };
    const int gthreads = N * 12;
    const int gather_blocks = (gthreads + 255) / 256;   // 2344
    u16*   hs        = (u16*)  carve((size_t)N * HID * 2);   // hs_raw / hs2
    u16*   hbuf      = (u16*)  carve((size_t)N * HID * 2);   // h1
    float* dinv      = (float*)carve((size_t)N * 4);
    int*   row_start = (int*)  carve((size_t)(N + 1) * 4);
    int*   csr_src   = (int*)  carve((size_t)E * 4);
    u32*   staging   = (u32*)  carve((size_t)E * 4);
    int*   hist64    = (int*)  carve((size_t)HIST_BLOCKS * 256 * 4);
    int*   bin_start = (int*)  carve(257 * 4);
    int*   bin_cursor= (int*)  carve(256 * 4);
    float* partials  = (float*)carve((size_t)gather_blocks * HID * 4);
    float* colsum    = (float*)carve((size_t)HID * 4);

    const int gemm_blocks = (N + 63) / 64;   // 782

    // K1: bin-hist (64 private) + layer-1 raw GEMM, fused role-split
    mega1_kernel<<<HIST_BLOCKS + gemm_blocks, 256, 0, stream>>>(
        dst, hist64, x, W1, hs, N, E);
    // K2-K4: CSR build
    binscan_kernel<<<1, 256, 0, stream>>>(hist64, bin_start, bin_cursor, NB, E);
    binappend_kernel<<<(E + AP_CHUNK - 1) / AP_CHUNK, 256, 0, stream>>>(
        src, dst, bin_cursor, staging, E);
    binplace_kernel<<<NB, 256, 0, stream>>>(staging, bin_start, row_start,
                                            dinv, csr_src, N, E, NB);
    // K5: layer-1 aggregation (dinv applied per gathered row)
    gather1_kernel<<<gather_blocks, 256, 0, stream>>>(
        (const uint4*)hs, row_start, csr_src, dinv, b1, (uint4*)hbuf, N);
    // K6: layer-2 GEMM (output pre-scaled by dinv)
    gemm2_kernel<<<gemm_blocks, 256, 0, stream>>>(hbuf, W2, dinv, hs, N);
    // K7: layer-2 aggregation fused with mean-pool partials
    gather2_pool_kernel<<<gather_blocks, 256, 0, stream>>>(
        (const uint4*)hs, row_start, csr_src, dinv, b2, partials, N);
    // K8-K9: reduce + heads
    reduce_partials<<<24, 256, 0, stream>>>((const float4*)partials, (float4*)colsum,
                                            gather_blocks);
    head_kernel<<<1, 128, 0, stream>>>(colsum, N, lin_w, lin_b,
        q_w, q_b, g_w, g_b, p_w, p_b, t_w, t_b, (float*)d_out);
}

// Round 9
// 111.754 us; speedup vs baseline: 4.4457x; 1.2298x over previous
//
#include <hip/hip_runtime.h>

#define HID 96
#define BIN_SHIFT 8     // 256 nodes per bin
#define AP_PER_T 16     // edges per thread in binappend
#define AP_CHUNK (256 * AP_PER_T)   // 4096 edges per WG
#define HIST_BLOCKS 64
#define FP8_STRIDE 128  // padded row: 96 fp8 + 32 pad = exactly one 128B line

typedef unsigned int u32;
typedef unsigned short u16;
typedef unsigned char u8;
typedef __attribute__((ext_vector_type(8))) short bf16x8;
typedef __attribute__((ext_vector_type(4))) float f32x4;
typedef __attribute__((ext_vector_type(2))) float f32x2;

// ---- bf16 helpers ----
__device__ __forceinline__ float bl(u32 u) { return __uint_as_float(u << 16); }
__device__ __forceinline__ float bh(u32 u) { return __uint_as_float(u & 0xFFFF0000u); }
__device__ __forceinline__ u16 f2bf(float f) {  // round-to-nearest-even
    u32 u = __float_as_uint(f);
    return (u16)((u + 0x7FFFu + ((u >> 16) & 1u)) >> 16);
}
__device__ __forceinline__ u32 packbf(float a, float b) {
    return (u32)f2bf(a) | ((u32)f2bf(b) << 16);
}

// ---- fp8 (OCP e4m3) helpers: HW cvt ----
__device__ __forceinline__ u8 f2fp8(float f) {
    return (u8)(__builtin_amdgcn_cvt_pk_fp8_f32(f, f, 0, false) & 0xFF);
}
// decode 4 fp8 from one u32, acc[k] += val*dv
__device__ __forceinline__ void acc4(float* acc, u32 w, float dv) {
    f32x2 a = __builtin_amdgcn_cvt_pk_f32_fp8((int)w, false);
    f32x2 b = __builtin_amdgcn_cvt_pk_f32_fp8((int)w, true);
    acc[0] = fmaf(a.x, dv, acc[0]); acc[1] = fmaf(a.y, dv, acc[1]);
    acc[2] = fmaf(b.x, dv, acc[2]); acc[3] = fmaf(b.y, dv, acc[3]);
}
__device__ __forceinline__ void acc16(float* acc, uint4 v, float dv) {
    acc4(acc + 0, v.x, dv); acc4(acc + 4, v.y, dv);
    acc4(acc + 8, v.z, dv); acc4(acc + 12, v.w, dv);
}

// ---------------- MFMA GEMM body ----------------
__device__ __forceinline__ bf16x8 load_a8(const u16* p) { return *(const bf16x8*)p; }
__device__ __forceinline__ bf16x8 load_a8(const float* p) {
    float4 v0 = *(const float4*)p;
    float4 v1 = *(const float4*)(p + 4);
    bf16x8 r;
    r[0] = (short)f2bf(v0.x); r[1] = (short)f2bf(v0.y);
    r[2] = (short)f2bf(v0.z); r[3] = (short)f2bf(v0.w);
    r[4] = (short)f2bf(v1.x); r[5] = (short)f2bf(v1.y);
    r[6] = (short)f2bf(v1.z); r[7] = (short)f2bf(v1.w);
    return r;
}

// out[i,:] = fp8( (SCALE ? dinv[i] : 1) * (in[i,:] @ W) ), row stride FP8_STRIDE
// W: [96 x 96] f32 row-major; staged to LDS bf16-transposed in-kernel.
template <typename TI, bool SCALE>
__device__ __forceinline__ void gemm_body(int bid, int t, const TI* __restrict__ xb,
        const float* __restrict__ W, const float* __restrict__ dinv,
        u8* __restrict__ out, int n, uint4* Wt4) {
    for (int idx = t; idx < 96 * 12; idx += 256) {
        int col = idx % 96, c = idx / 96;
        const float* wp = W + c * 8 * 96 + col;
        uint4 pk;
        pk.x = packbf(wp[0],   wp[96]);
        pk.y = packbf(wp[192], wp[288]);
        pk.z = packbf(wp[384], wp[480]);
        pk.w = packbf(wp[576], wp[672]);
        Wt4[col * 13 + c] = pk;
    }
    __syncthreads();

    int wave = t >> 6, lane = t & 63;
    int row0 = bid * 64 + wave * 16;
    int kb = lane >> 4;              // 0..3 (k-block)
    int rc = lane & 15;              // row (A) / col (B,C) within tile
    int arow = row0 + rc;
    int ar = (arow < n) ? arow : 0;

    const TI* ap = xb + (size_t)ar * 96 + kb * 8;
    bf16x8 a0 = load_a8(ap);
    bf16x8 a1 = load_a8(ap + 32);
    bf16x8 a2 = load_a8(ap + 64);

    const u16* wbase = (const u16*)Wt4;
    f32x4 acc[6];
#pragma unroll
    for (int j = 0; j < 6; ++j) acc[j] = (f32x4){0.f, 0.f, 0.f, 0.f};

#pragma unroll
    for (int j = 0; j < 6; ++j) {
        int col = j * 16 + rc;
        const u16* wp = wbase + col * 104 + kb * 8;
        bf16x8 b0 = *(const bf16x8*)(wp);
        bf16x8 b1 = *(const bf16x8*)(wp + 32);
        bf16x8 b2 = *(const bf16x8*)(wp + 64);
        acc[j] = __builtin_amdgcn_mfma_f32_16x16x32_bf16(a0, b0, acc[j], 0, 0, 0);
        acc[j] = __builtin_amdgcn_mfma_f32_16x16x32_bf16(a1, b1, acc[j], 0, 0, 0);
        acc[j] = __builtin_amdgcn_mfma_f32_16x16x32_bf16(a2, b2, acc[j], 0, 0, 0);
    }

    // C/D layout: col = rc, row = kb*4 + r  [m89-verified]
#pragma unroll
    for (int r = 0; r < 4; ++r) {
        int row = row0 + kb * 4 + r;
        if (row < n) {
            float dv = SCALE ? dinv[row] : 1.0f;
            u8* orow = out + (size_t)row * FP8_STRIDE + rc;
#pragma unroll
            for (int j = 0; j < 6; ++j)
                orow[j * 16] = f2fp8(dv * acc[j][r]);
        }
    }
}

// ---------------- K1: fused bin-histogram + layer-1 GEMM ----------------
__global__ __launch_bounds__(256) void mega1_kernel(const int* __restrict__ dst,
        int* __restrict__ hist64, const float* __restrict__ x,
        const float* __restrict__ W1, u8* __restrict__ hs_raw, int n, int E) {
    __shared__ uint4 smem[96 * 13];
    int b = blockIdx.x;
    int t = threadIdx.x;
    if (b < HIST_BLOCKS) {
        int* h = (int*)smem;
        h[t] = 0;
        __syncthreads();
        for (int e = b * 256 + t; e < E; e += HIST_BLOCKS * 256)
            atomicAdd(&h[dst[e] >> BIN_SHIFT], 1);
        __syncthreads();
        hist64[b * 256 + t] = h[t];
    } else {
        gemm_body<float, false>(b - HIST_BLOCKS, t, x, W1, nullptr, hs_raw, n, smem);
    }
}

// ---------------- K2: scan of 64 private histograms ----------------
__global__ __launch_bounds__(256) void binscan_kernel(const int* __restrict__ hist64,
        int* __restrict__ bin_start, int* __restrict__ bin_cursor, int nb, int E) {
    __shared__ int sh[256];
    int t = threadIdx.x;
    int s = 0;
#pragma unroll 8
    for (int b = 0; b < HIST_BLOCKS; ++b) s += hist64[b * 256 + t];
    sh[t] = s;
    __syncthreads();
    for (int off = 1; off < 256; off <<= 1) {
        int v = (t >= off) ? sh[t - off] : 0;
        __syncthreads();
        sh[t] += v;
        __syncthreads();
    }
    if (t < nb) {
        int st = (t == 0) ? 0 : sh[t - 1];
        bin_start[t] = st;
        bin_cursor[t] = st;
    }
    if (t == 0) bin_start[nb] = E;
}

// ---------------- K3: partition edges into bin-grouped staging ----------------
__global__ __launch_bounds__(256) void binappend_kernel(const int* __restrict__ src,
        const int* __restrict__ dst, int* __restrict__ bin_cursor,
        u32* __restrict__ staging, int E) {
    __shared__ int cnt[256];
    __shared__ int pos[256];
    int t = threadIdx.x;
    cnt[t] = 0;
    __syncthreads();
    int base = blockIdx.x * AP_CHUNK + t;
    u32 pw[AP_PER_T];
    int bn[AP_PER_T];
#pragma unroll
    for (int j = 0; j < AP_PER_T; ++j) {
        int e = base + j * 256;
        if (e < E) {
            int s = src[e], d = dst[e];
            pw[j] = (u32)s | ((u32)(d & 255) << 24);
            bn[j] = d >> BIN_SHIFT;
            atomicAdd(&cnt[bn[j]], 1);
        } else bn[j] = -1;
    }
    __syncthreads();
    if (cnt[t]) pos[t] = atomicAdd(&bin_cursor[t], cnt[t]);
    __syncthreads();
#pragma unroll
    for (int j = 0; j < AP_PER_T; ++j) {
        if (bn[j] >= 0) {
            int p = atomicAdd(&pos[bn[j]], 1);
            staging[p] = pw[j];
        }
    }
}

// ---------------- K4: per-bin place ----------------
__global__ __launch_bounds__(256) void binplace_kernel(const u32* __restrict__ staging,
        const int* __restrict__ bin_start, int* __restrict__ row_start,
        float* __restrict__ dinv, int* __restrict__ csr_src, int n, int E, int nb) {
    __shared__ int ncnt[256];
    __shared__ int sh[256];
    __shared__ int nstart[256];
    int b = blockIdx.x;
    int t = threadIdx.x;
    int nbase = b << BIN_SHIFT;
    int nnodes = min(256, n - nbase);
    int s0 = bin_start[b], s1 = bin_start[b + 1];
    ncnt[t] = 0;
    __syncthreads();
    for (int e = s0 + t; e < s1; e += 256)
        atomicAdd(&ncnt[staging[e] >> 24], 1);
    __syncthreads();
    int v0 = ncnt[t];
    sh[t] = v0;
    __syncthreads();
    for (int off = 1; off < 256; off <<= 1) {
        int v = (t >= off) ? sh[t - off] : 0;
        __syncthreads();
        sh[t] += v;
        __syncthreads();
    }
    int mystart = s0 + sh[t] - v0;
    if (t < nnodes) {
        row_start[nbase + t] = mystart;
        dinv[nbase + t] = 1.0f / sqrtf((float)(v0 + 1));  // +1 self-loop
        nstart[t] = mystart;
    }
    if (b == nb - 1 && t == 0) row_start[n] = E;
    __syncthreads();
    for (int e = s0 + t; e < s1; e += 256) {
        u32 pr = staging[e];
        int slot = atomicAdd(&nstart[pr >> 24], 1);
        csr_src[slot] = (int)(pr & 0xFFFFFFu);
    }
}

// ---------------- K5: gather1 (fp8 table, apply dinv[s] per row) ----------------
// thread per (node, 16B chunk q<6); out h1 bf16 [n x 96]
__global__ void gather1_kernel(const uint4* __restrict__ hs, const int* __restrict__ row_start,
        const int* __restrict__ csr_src, const float* __restrict__ dinv,
        const float* __restrict__ bias, uint4* __restrict__ out, int n) {
    int gid = blockIdx.x * blockDim.x + threadIdx.x;
    if (gid >= n * 6) return;
    int i = gid / 6, q = gid - i * 6;
    float dvi = dinv[i];
    float acc[16];
#pragma unroll
    for (int j = 0; j < 16; ++j) acc[j] = 0.f;
    acc16(acc, hs[i * 8 + q], dvi);    // self-loop (unscaled table, weight dvi)
    int e = row_start[i], e1 = row_start[i + 1];
    for (; e + 1 < e1; e += 2) {
        int s0 = csr_src[e], s1 = csr_src[e + 1];
        float dv0 = dinv[s0], dv1 = dinv[s1];
        uint4 a = hs[s0 * 8 + q];
        uint4 b = hs[s1 * 8 + q];
        acc16(acc, a, dv0);
        acc16(acc, b, dv1);
    }
    if (e < e1) {
        int s0 = csr_src[e];
        acc16(acc, hs[s0 * 8 + q], dinv[s0]);
    }
    const float4 b0 = reinterpret_cast<const float4*>(bias)[q * 4 + 0];
    const float4 b1 = reinterpret_cast<const float4*>(bias)[q * 4 + 1];
    const float4 b2 = reinterpret_cast<const float4*>(bias)[q * 4 + 2];
    const float4 b3 = reinterpret_cast<const float4*>(bias)[q * 4 + 3];
    float r[16];
    r[0]  = fmaxf(fmaf(acc[0],  dvi, b0.x), 0.f);
    r[1]  = fmaxf(fmaf(acc[1],  dvi, b0.y), 0.f);
    r[2]  = fmaxf(fmaf(acc[2],  dvi, b0.z), 0.f);
    r[3]  = fmaxf(fmaf(acc[3],  dvi, b0.w), 0.f);
    r[4]  = fmaxf(fmaf(acc[4],  dvi, b1.x), 0.f);
    r[5]  = fmaxf(fmaf(acc[5],  dvi, b1.y), 0.f);
    r[6]  = fmaxf(fmaf(acc[6],  dvi, b1.z), 0.f);
    r[7]  = fmaxf(fmaf(acc[7],  dvi, b1.w), 0.f);
    r[8]  = fmaxf(fmaf(acc[8],  dvi, b2.x), 0.f);
    r[9]  = fmaxf(fmaf(acc[9],  dvi, b2.y), 0.f);
    r[10] = fmaxf(fmaf(acc[10], dvi, b2.z), 0.f);
    r[11] = fmaxf(fmaf(acc[11], dvi, b2.w), 0.f);
    r[12] = fmaxf(fmaf(acc[12], dvi, b3.x), 0.f);
    r[13] = fmaxf(fmaf(acc[13], dvi, b3.y), 0.f);
    r[14] = fmaxf(fmaf(acc[14], dvi, b3.z), 0.f);
    r[15] = fmaxf(fmaf(acc[15], dvi, b3.w), 0.f);
    uint4 o0, o1;
    o0.x = packbf(r[0], r[1]);   o0.y = packbf(r[2], r[3]);
    o0.z = packbf(r[4], r[5]);   o0.w = packbf(r[6], r[7]);
    o1.x = packbf(r[8], r[9]);   o1.y = packbf(r[10], r[11]);
    o1.z = packbf(r[12], r[13]); o1.w = packbf(r[14], r[15]);
    out[i * 12 + q * 2] = o0;
    out[i * 12 + q * 2 + 1] = o1;
}

// ---------------- K6: gemm2 (h1 bf16 -> hs2 fp8, pre-scaled by dinv) ----------------
__global__ __launch_bounds__(256) void gemm2_kernel(const u16* __restrict__ xb,
        const float* __restrict__ W, const float* __restrict__ dinv,
        u8* __restrict__ out, int n) {
    __shared__ uint4 smem[96 * 13];
    gemm_body<u16, true>(blockIdx.x, threadIdx.x, xb, W, dinv, out, n, smem);
}

// ---------------- K7: gather2 fused with mean-pool partials ----------------
__global__ __launch_bounds__(256) void gather2_pool_kernel(const uint4* __restrict__ hs,
        const int* __restrict__ row_start, const int* __restrict__ csr_src,
        const float* __restrict__ dinv, const float* __restrict__ bias,
        float* __restrict__ partials, int n) {
    __shared__ float sh[43][96];
    int t = threadIdx.x;
    for (int idx = t; idx < 43 * 96; idx += 256) (&sh[0][0])[idx] = 0.f;
    __syncthreads();

    int gid = blockIdx.x * blockDim.x + t;
    float r[16];
#pragma unroll
    for (int j = 0; j < 16; ++j) r[j] = 0.f;
    int q = 0;
    if (gid < n * 6) {
        int i = gid / 6; q = gid - i * 6;
        float acc[16];
#pragma unroll
        for (int j = 0; j < 16; ++j) acc[j] = 0.f;
        acc16(acc, hs[i * 8 + q], 1.0f);   // self (pre-scaled table)
        int e = row_start[i], e1 = row_start[i + 1];
        for (; e + 1 < e1; e += 2) {
            int s0 = csr_src[e], s1 = csr_src[e + 1];
            uint4 a = hs[s0 * 8 + q];
            uint4 b = hs[s1 * 8 + q];
            acc16(acc, a, 1.0f);
            acc16(acc, b, 1.0f);
        }
        if (e < e1) acc16(acc, hs[csr_src[e] * 8 + q], 1.0f);
        float dv = dinv[i];
        const float4 b0 = reinterpret_cast<const float4*>(bias)[q * 4 + 0];
        const float4 b1 = reinterpret_cast<const float4*>(bias)[q * 4 + 1];
        const float4 b2 = reinterpret_cast<const float4*>(bias)[q * 4 + 2];
        const float4 b3 = reinterpret_cast<const float4*>(bias)[q * 4 + 3];
        r[0]  = fmaxf(fmaf(acc[0],  dv, b0.x), 0.f);
        r[1]  = fmaxf(fmaf(acc[1],  dv, b0.y), 0.f);
        r[2]  = fmaxf(fmaf(acc[2],  dv, b0.z), 0.f);
        r[3]  = fmaxf(fmaf(acc[3],  dv, b0.w), 0.f);
        r[4]  = fmaxf(fmaf(acc[4],  dv, b1.x), 0.f);
        r[5]  = fmaxf(fmaf(acc[5],  dv, b1.y), 0.f);
        r[6]  = fmaxf(fmaf(acc[6],  dv, b1.z), 0.f);
        r[7]  = fmaxf(fmaf(acc[7],  dv, b1.w), 0.f);
        r[8]  = fmaxf(fmaf(acc[8],  dv, b2.x), 0.f);
        r[9]  = fmaxf(fmaf(acc[9],  dv, b2.y), 0.f);
        r[10] = fmaxf(fmaf(acc[10], dv, b2.z), 0.f);
        r[11] = fmaxf(fmaf(acc[11], dv, b2.w), 0.f);
        r[12] = fmaxf(fmaf(acc[12], dv, b3.x), 0.f);
        r[13] = fmaxf(fmaf(acc[13], dv, b3.y), 0.f);
        r[14] = fmaxf(fmaf(acc[14], dv, b3.z), 0.f);
        r[15] = fmaxf(fmaf(acc[15], dv, b3.w), 0.f);
    }
    // per-block column partials: group g = t/6; its 6 threads cover q=0..5 (distinct)
    int g = t / 6;
#pragma unroll
    for (int j = 0; j < 16; ++j) sh[g][q * 16 + j] += r[j];
    __syncthreads();
    if (t < 96) {
        float s = 0.f;
#pragma unroll
        for (int gg = 0; gg < 43; ++gg) s += sh[gg][t];
        partials[blockIdx.x * 96 + t] = s;
    }
}

// ---------------- K8: reduce partials ----------------
__global__ __launch_bounds__(256) void reduce_partials(const float4* __restrict__ partials,
        float4* __restrict__ colsum, int nb) {
    int q = blockIdx.x;
    int t = threadIdx.x;
    float4 acc = {0.f, 0.f, 0.f, 0.f};
    for (int b = t; b < nb; b += 256) {
        float4 v = partials[b * 24 + q];
        acc.x += v.x; acc.y += v.y; acc.z += v.z; acc.w += v.w;
    }
    __shared__ float4 sh[256];
    sh[t] = acc;
    __syncthreads();
    for (int off = 128; off > 0; off >>= 1) {
        if (t < off) {
            sh[t].x += sh[t + off].x; sh[t].y += sh[t + off].y;
            sh[t].z += sh[t + off].z; sh[t].w += sh[t + off].w;
        }
        __syncthreads();
    }
    if (t == 0) colsum[q] = sh[0];
}

// ---------------- K9: final MLP heads ----------------
__global__ __launch_bounds__(128) void head_kernel(const float* __restrict__ colsum, int n,
        const float* __restrict__ lin_w, const float* __restrict__ lin_b,
        const float* __restrict__ q_w, const float* __restrict__ q_b,
        const float* __restrict__ g_w, const float* __restrict__ g_b,
        const float* __restrict__ p_w, const float* __restrict__ p_b,
        const float* __restrict__ t_w, const float* __restrict__ t_b,
        float* __restrict__ out) {
    __shared__ float hm[96];
    __shared__ float h[96];
    int t = threadIdx.x;
    if (t < 96) hm[t] = colsum[t] / (float)n;
    __syncthreads();
    if (t < 96) {
        float s = lin_b[t];
        for (int k = 0; k < 96; ++k) s = fmaf(hm[k], lin_w[k * 96 + t], s);
        h[t] = fmaxf(s, 0.f);
    }
    __syncthreads();
    if (t < 43) {
        float s;
        if (t < 16) {
            s = q_b[t];
            for (int k = 0; k < 96; ++k) s = fmaf(h[k], q_w[k * 16 + t], s);
        } else if (t < 24) {
            int j = t - 16;
            s = g_b[j];
            for (int k = 0; k < 96; ++k) s = fmaf(h[k], g_w[k * 8 + j], s);
        } else if (t < 28) {
            int j = t - 24;
            s = p_b[j];
            for (int k = 0; k < 96; ++k) s = fmaf(h[k], p_w[k * 4 + j], s);
        } else {
            int j = t - 28;
            s = t_b[j];
            for (int k = 0; k < 96; ++k) s = fmaf(h[k], t_w[k * 15 + j], s);
        }
        out[t] = s;
    }
}

extern "C" void kernel_launch(void* const* d_in, const int* in_sizes, int n_in,
                              void* d_out, int out_size, void* d_ws, size_t ws_size,
                              hipStream_t stream) {
    const float* x     = (const float*)d_in[0];
    const int*   edges = (const int*)d_in[1];
    const float* W1    = (const float*)d_in[2];
    const float* b1    = (const float*)d_in[3];
    const float* W2    = (const float*)d_in[4];
    const float* b2    = (const float*)d_in[5];
    const float* lin_w = (const float*)d_in[6];
    const float* lin_b = (const float*)d_in[7];
    const float* q_w   = (const float*)d_in[8];
    const float* q_b   = (const float*)d_in[9];
    const float* g_w   = (const float*)d_in[10];
    const float* g_b   = (const float*)d_in[11];
    const float* p_w   = (const float*)d_in[12];
    const float* p_b   = (const float*)d_in[13];
    const float* t_w   = (const float*)d_in[14];
    const float* t_b   = (const float*)d_in[15];

    const int N = in_sizes[0] / HID;   // 50000
    const int E = in_sizes[1] / 2;     // 800000
    const int* src = edges;
    const int* dst = edges + E;
    const int NB = (N + 255) >> BIN_SHIFT;   // 196

    char* w = (char*)d_ws;
    auto carve = [&](size_t bytes) {
        char* p = w;
        w += (bytes + 255) & ~size_t(255);
        return (void*)p;
    };
    const int gthreads = N * 6;
    const int gather_blocks = (gthreads + 255) / 256;   // 1172
    u8*    hs        = (u8*)   carve((size_t)N * FP8_STRIDE);  // fp8 tables (reused)
    u16*   hbuf      = (u16*)  carve((size_t)N * HID * 2);     // h1 bf16
    float* dinv      = (float*)carve((size_t)N * 4);
    int*   row_start = (int*)  carve((size_t)(N + 1) * 4);
    int*   csr_src   = (int*)  carve((size_t)E * 4);
    u32*   staging   = (u32*)  carve((size_t)E * 4);
    int*   hist64    = (int*)  carve((size_t)HIST_BLOCKS * 256 * 4);
    int*   bin_start = (int*)  carve(257 * 4);
    int*   bin_cursor= (int*)  carve(256 * 4);
    float* partials  = (float*)carve((size_t)gather_blocks * HID * 4);
    float* colsum    = (float*)carve((size_t)HID * 4);

    const int gemm_blocks = (N + 63) / 64;   // 782

    // K1: bin-hist + layer-1 raw GEMM (fp8 out)
    mega1_kernel<<<HIST_BLOCKS + gemm_blocks, 256, 0, stream>>>(
        dst, hist64, x, W1, hs, N, E);
    // K2-K4: CSR build
    binscan_kernel<<<1, 256, 0, stream>>>(hist64, bin_start, bin_cursor, NB, E);
    binappend_kernel<<<(E + AP_CHUNK - 1) / AP_CHUNK, 256, 0, stream>>>(
        src, dst, bin_cursor, staging, E);
    binplace_kernel<<<NB, 256, 0, stream>>>(staging, bin_start, row_start,
                                            dinv, csr_src, N, E, NB);
    // K5: layer-1 aggregation (fp8 gather, dinv per source row)
    gather1_kernel<<<gather_blocks, 256, 0, stream>>>(
        (const uint4*)hs, row_start, csr_src, dinv, b1, (uint4*)hbuf, N);
    // K6: layer-2 GEMM (fp8 out, pre-scaled)
    gemm2_kernel<<<gemm_blocks, 256, 0, stream>>>(hbuf, W2, dinv, hs, N);
    // K7: layer-2 aggregation fused with mean-pool partials
    gather2_pool_kernel<<<gather_blocks, 256, 0, stream>>>(
        (const uint4*)hs, row_start, csr_src, dinv, b2, partials, N);
    // K8-K9: reduce + heads
    reduce_partials<<<24, 256, 0, stream>>>((const float4*)partials, (float4*)colsum,
                                            gather_blocks);
    head_kernel<<<1, 128, 0, stream>>>(colsum, N, lin_w, lin_b,
        q_w, q_b, g_w, g_b, p_w, p_b, t_w, t_b, (float*)d_out);
}